// Round 5
// baseline (149.196 us; speedup 1.0000x reference)
//
#include <hip/hip_runtime.h>
#include <cstdint>

#define NPRI 33600
#define NGT  256
#define NCLS 80
#define KTOP 13
#define INF_F 1.0e8f
#define EPS_F 1e-7f
#define L10 3.3219280948873623f
#define SCN_T 1024
#define NW   (SCN_T / 64)                   // 16 waves per block
#define CAPC 1024                  // per-GT cost candidates (full range)
#define RFIX 5.5f                  // fixed collect radius (strides); Dmax typically ~4.7
#define PREP_BLKS ((NPRI + 255) / 256)
#define NEGINF __int_as_float(0xff800000)

typedef unsigned long long u64;

__device__ __forceinline__ int get_label(const void* p, int j, int is64) {
    if (is64) return (int)((const long long*)p)[j];
    return ((const int*)p)[j];
}

// ---------- wave helpers (reduce + broadcast) ----------
__device__ __forceinline__ float wave_max_bc_f32(float v) {
    #pragma unroll
    for (int off = 32; off > 0; off >>= 1) v = fmaxf(v, __shfl_down(v, off, 64));
    return __int_as_float(__builtin_amdgcn_readfirstlane(__float_as_int(v)));
}
__device__ __forceinline__ u64 wave_min_bc_u64(u64 v) {
    #pragma unroll
    for (int off = 32; off > 0; off >>= 1) { u64 o = __shfl_down(v, off, 64); v = (o < v) ? o : v; }
    unsigned lo = (unsigned)__builtin_amdgcn_readfirstlane((int)(v & 0xffffffffull));
    unsigned hi = (unsigned)__builtin_amdgcn_readfirstlane((int)(v >> 32));
    return (((u64)hi) << 32) | lo;
}
// ascending 13-list insert (l[0] = smallest); caller guards v > l[0]
__device__ __forceinline__ void insert_max13(float (&l)[KTOP], float v) {
    l[0] = v;
    #pragma unroll
    for (int s = 0; s < KTOP - 1; ++s)
        if (l[s] > l[s + 1]) { float t = l[s]; l[s] = l[s + 1]; l[s + 1] = t; }
}
// f32 multiset per-wave top-13: ballot single-lane elimination preserves duplicates
template<int NSL>
__device__ __forceinline__ void wave_merge_max13_f32(float (&l)[NSL], float* dst, int lane) {
    int p = 0;
    for (int r = 0; r < KTOP; ++r) {
        float cur = NEGINF;
        #pragma unroll
        for (int s = 0; s < NSL; ++s) if (s == p) cur = l[NSL - 1 - s];
        float bm = wave_max_bc_f32(cur);
        u64 m = __ballot(cur == bm && bm != NEGINF);
        int first = __ffsll(m) - 1;
        if (lane == first) p++;
        if (lane == 0) dst[r] = bm;
    }
}
// u64 per-wave top-13 min (keys idx-distinct -> single match per round)
template<int NSL>
__device__ __forceinline__ void wave_merge_minN(u64 (&l)[NSL], u64* dst, int lane) {
    int p = 0;
    for (int r = 0; r < KTOP; ++r) {
        u64 cur = ~0ull;
        #pragma unroll
        for (int s = 0; s < NSL; ++s) if (s == p) cur = l[s];
        u64 bm = wave_min_bc_u64(cur);
        if (cur == bm && bm != ~0ull) p++;
        if (lane == 0) dst[r] = bm;
    }
}

// ---------- exact formulas (verbatim: bit-identical selection) ----------
__device__ __forceinline__ float iou_exact(float4 pb, float areap, float gx1, float gy1,
                                           float gx2, float gy2, float areag) {
    float iw = fmaxf(fminf(pb.z, gx2) - fmaxf(pb.x, gx1), 0.0f);
    float ih = fmaxf(fminf(pb.w, gy2) - fmaxf(pb.y, gy1), 0.0f);
    float inter = iw * ih;
    return inter / fmaxf(areap + areag - inter, 1e-6f);
}
__device__ __forceinline__ float cost_exact(float4 p2, float gcx, float gcy,
                                            float l, float iou) {
    float dx = p2.x - gcx, dy = p2.y - gcy;
    float dist = sqrtf(dx * dx + dy * dy) / p2.z;
    float soft = exp2f((dist - 3.0f) * L10);
    float sig = 1.0f / (1.0f + expf(-l));
    float dd = iou - sig;
    float bce = fmaxf(l, 0.0f) - l * iou + log1pf(expf(-fabsf(l)));
    float iouc = -logf(iou + EPS_F) * 3.0f;
    return bce * (dd * dd) + iouc + soft;
}

// ---------- prep: detect int64 + init + valid mask + packed array ----------
__global__ __launch_bounds__(256) void k_prep(
        const float* __restrict__ priors, const float* __restrict__ gt,
        const void* labels, const float* __restrict__ pboxes,
        float4* __restrict__ pbp,
        int* count, int* firstgt, int* flag) {
    __shared__ float4 gbox[NGT];
    __shared__ int    gpad[NGT];
    __shared__ int    bad;
    const int tid = threadIdx.x;
    const int b = blockIdx.x;
    if (b == 0 && tid == 0) bad = 0;
    {
        float4 bx = ((const float4*)gt)[tid];
        gbox[tid] = bx;
        gpad[tid] = ((bx.x + bx.y + bx.z + bx.w) > 0.0f) ? 1 : 0;
    }
    __syncthreads();
    if (b == 0 && tid < 128) {
        long long v = ((const long long*)labels)[tid];   // first 1024B: in-bounds either layout
        if (v < 0 || v >= NCLS) atomicOr(&bad, 1);
    }
    int i = b * 256 + tid;
    if (i < NPRI) {
        count[i] = 0; firstgt[i] = NGT;
        float4 pr = ((const float4*)priors)[i];
        float px = pr.x, py = pr.y;
        int v = 0;
        for (int j = 0; j < NGT; ++j) {
            float4 bx = gbox[j];
            float m = fminf(fminf(px - bx.x, py - bx.y), fminf(bx.z - px, bx.w - py));
            if (m > 0.0f && gpad[j]) { v = 1; break; }
        }
        pbp[2 * i]     = ((const float4*)pboxes)[i];
        pbp[2 * i + 1] = make_float4(px, py, pr.z, v ? 1.0f : 0.0f);
    }
    if (b == 0) {
        __syncthreads();
        if (tid == 0) *flag = bad ? 0 : 1;   // 1 => int64 layout
    }
}

// one scan step: copy buffer out, immediately reload it for (it+4), compute.
// Rotate-in-place keeps 8 loads (4x pb + 4x p2) in flight ~800cy ahead.
#define STEP(K, PB, P2) { \
    const int i = i0 + (it + K) * SCN_T; \
    float4 pbc = PB; float4 p2c = P2; \
    int ip = i + 4 * SCN_T; \
    int ic = (ip < NPRI) ? ip : i0; \
    PB = pbp[2 * ic]; \
    P2 = pbp[2 * ic + 1]; \
    if (i < NPRI) { \
        float areap = (pbc.z - pbc.x) * (pbc.w - pbc.y); \
        float iw = fmaxf(fminf(pbc.z, gx2) - fmaxf(pbc.x, gx1), 0.0f); \
        float ih = fmaxf(fminf(pbc.w, gy2) - fmaxf(pbc.y, gy1), 0.0f); \
        float inter = iw * ih; \
        float iou = inter / fmaxf(areap + areag - inter, 1e-6f); \
        if (iou > 0.0f && iou > lfi[0]) insert_max13(lfi, iou); \
        if (p2c.w != 0.0f) { \
            float dx = p2c.x - gcx, dy = p2c.y - gcy; \
            float rad = p2c.z * RFIX; \
            if (dx * dx + dy * dy <= rad * rad * (1.0f + 1e-5f)) { \
                int p = atomicAdd(&s_nc, 1); \
                if (p < CAPC) lcost[p] = i; \
            } \
        } \
    } \
}

// ---------- one block per GT: full scan (reg top-13 iou) + merge + scatter ----------
__global__ __launch_bounds__(SCN_T) void k_scan(
        const float* __restrict__ scores,
        const float4* __restrict__ pbp,
        const float* __restrict__ gt, const void* labels, const int* flag,
        int* count, int* firstgt) {
    const int tid = threadIdx.x, lane = tid & 63, wid = tid >> 6;
    const int j = blockIdx.x;
    const int is64 = *flag;

    const float4 gb = ((const float4*)gt)[j];
    const float gx1 = gb.x, gy1 = gb.y, gx2 = gb.z, gy2 = gb.w;
    const float areag = (gx2 - gx1) * (gy2 - gy1);
    const float gcx = (gx1 + gx2) * 0.5f, gcy = (gy1 + gy2) * 0.5f;
    const int lab = get_label(labels, j, is64);

    __shared__ int s_nc, s_mode;
    __shared__ float s_dmax;
    __shared__ int lcost[CAPC];
    __shared__ float wiof[NW * KTOP];   // 16 per-wave iou top-13 lists
    __shared__ u64 wco[NW * KTOP];      // mode-2 fallback only
    __shared__ u64 csel[KTOP];
    __shared__ float s_iou13[KTOP];
    if (tid == 0) s_nc = 0;
    __syncthreads();

    // ---- single pass over all priors; per-lane register iou top-13 ----
    float lfi[KTOP];
    #pragma unroll
    for (int s = 0; s < KTOP; ++s) lfi[s] = NEGINF;
    {
        const int i0 = tid;
        float4 pb0 = pbp[2 * i0],               p20 = pbp[2 * i0 + 1];
        float4 pb1 = pbp[2 * (i0 + SCN_T)],     p21 = pbp[2 * (i0 + SCN_T) + 1];
        float4 pb2 = pbp[2 * (i0 + 2 * SCN_T)], p22 = pbp[2 * (i0 + 2 * SCN_T) + 1];
        float4 pb3 = pbp[2 * (i0 + 3 * SCN_T)], p23 = pbp[2 * (i0 + 3 * SCN_T) + 1];
        for (int it = 0; it < 36; it += 4) {     // covers i = tid + {0..35}*1024 >= NPRI range
            STEP(0, pb0, p20)
            STEP(1, pb1, p21)
            STEP(2, pb2, p22)
            STEP(3, pb3, p23)
        }
    }
    __syncthreads();
    const int nc = s_nc;
    const int ncc = (nc < CAPC) ? nc : CAPC;

    // every wave folds its 64 lane-lists into one 13-list
    wave_merge_max13_f32<KTOP>(lfi, &wiof[wid * KTOP], lane);
    __syncthreads();

    // ---- wave 0 = cost merge; wave 1 = iou cross-merge (parallel) ----
    if (wid == 0) {
        u64 lf[KTOP];
        #pragma unroll
        for (int s = 0; s < KTOP; ++s) lf[s] = ~0ull;
        for (int k = lane; k < ncc; k += 64) {   // <=16 per lane; 13-deep list complete
            int i = lcost[k];
            float4 pb = pbp[2 * i];
            float4 p2 = pbp[2 * i + 1];
            float areap = (pb.z - pb.x) * (pb.w - pb.y);
            float iou = iou_exact(pb, areap, gx1, gy1, gx2, gy2, areag);
            float ec = cost_exact(p2, gcx, gcy, scores[(size_t)i * NCLS + lab], iou);
            u64 ck = (((u64)__float_as_uint(ec)) << 32) | (unsigned)i;
            if (ck < lf[KTOP - 1]) {
                lf[KTOP - 1] = ck;
                #pragma unroll
                for (int s = KTOP - 1; s > 0; --s)
                    if (lf[s] < lf[s - 1]) { u64 t = lf[s]; lf[s] = lf[s - 1]; lf[s - 1] = t; }
            }
        }
        wave_merge_minN<KTOP>(lf, csel, lane);
        if (lane == 0) {
            u64 tk = csel[KTOP - 1];
            int mode; float dmax = 0.0f;
            if (tk == ~0ull) mode = 2;               // <13 candidates in RFIX ball
            else {
                float tau = __uint_as_float((unsigned)(tk >> 32));
                if (!(tau < 9.0e7f)) mode = 2;       // INF-ambiguity zone
                else {
                    dmax = 3.0f + __log2f(tau + 1e-5f) * (1.0f / L10) + 4e-3f;
                    mode = (dmax > RFIX || nc > CAPC) ? 1 : 0;
                }
            }
            s_mode = mode; s_dmax = dmax;
        }
    } else if (wid == 1) {
        // cross-merge the 16 per-wave iou lists -> s_iou13 (descending, multiset)
        int p = 0;
        for (int r = 0; r < KTOP; ++r) {
            float cur = (lane < NW && p < KTOP) ? wiof[lane * KTOP + p] : NEGINF;
            float bm = wave_max_bc_f32(cur);
            u64 m = __ballot(cur == bm && bm != NEGINF);
            int first = __ffsll(m) - 1;
            if (lane == first) p++;
            if (lane == 0) s_iou13[r] = bm;
        }
    }
    __syncthreads();

    int mode = s_mode;
    if (mode == 1) {   // re-collect at the sound radius Dmax' (rare)
        const float dmax = s_dmax;
        if (tid == 0) s_nc = 0;
        __syncthreads();
        for (int i = tid; i < NPRI; i += SCN_T) {
            float4 p2 = pbp[2 * i + 1];
            if (p2.w != 0.0f) {
                float dx = p2.x - gcx, dy = p2.y - gcy;
                float rad = p2.z * dmax;
                if (dx * dx + dy * dy <= rad * rad * (1.0f + 1e-5f)) {
                    int p = atomicAdd(&s_nc, 1);
                    if (p < CAPC) lcost[p] = i;
                }
            }
        }
        __syncthreads();
        int nc2 = s_nc;
        if (nc2 <= CAPC) {
            if (wid == 0) {
                u64 lf[KTOP];
                #pragma unroll
                for (int s = 0; s < KTOP; ++s) lf[s] = ~0ull;
                for (int k = lane; k < nc2; k += 64) {
                    int i = lcost[k];
                    float4 pb = pbp[2 * i];
                    float4 p2 = pbp[2 * i + 1];
                    float areap = (pb.z - pb.x) * (pb.w - pb.y);
                    float iou = iou_exact(pb, areap, gx1, gy1, gx2, gy2, areag);
                    float ec = cost_exact(p2, gcx, gcy, scores[(size_t)i * NCLS + lab], iou);
                    u64 ck = (((u64)__float_as_uint(ec)) << 32) | (unsigned)i;
                    if (ck < lf[KTOP - 1]) {
                        lf[KTOP - 1] = ck;
                        #pragma unroll
                        for (int s = KTOP - 1; s > 0; --s)
                            if (lf[s] < lf[s - 1]) { u64 t = lf[s]; lf[s] = lf[s - 1]; lf[s - 1] = t; }
                    }
                }
                wave_merge_minN<KTOP>(lf, csel, lane);
            }
        } else {
            mode = 2;   // uniform (s_nc shared)
        }
        __syncthreads();
    }
    if (mode == 2) {   // exact full scan (correctness net)
        u64 lf[KTOP];
        #pragma unroll
        for (int s = 0; s < KTOP; ++s) lf[s] = ~0ull;
        for (int i = tid; i < NPRI; i += SCN_T) {
            float4 pb = pbp[2 * i];
            float4 p2 = pbp[2 * i + 1];
            float areap = (pb.z - pb.x) * (pb.w - pb.y);
            float iou = iou_exact(pb, areap, gx1, gy1, gx2, gy2, areag);
            float ec = INF_F;
            if (p2.w != 0.0f) ec = cost_exact(p2, gcx, gcy, scores[(size_t)i * NCLS + lab], iou);
            u64 k2 = (((u64)__float_as_uint(ec)) << 32) | (unsigned)i;
            if (k2 < lf[KTOP - 1]) {
                lf[KTOP - 1] = k2;
                #pragma unroll
                for (int s = KTOP - 1; s > 0; --s)
                    if (lf[s] < lf[s - 1]) { u64 t = lf[s]; lf[s] = lf[s - 1]; lf[s - 1] = t; }
            }
        }
        wave_merge_minN<KTOP>(lf, &wco[wid * KTOP], lane);
        __syncthreads();
        if (wid == 0) {
            int p = 0;
            for (int r = 0; r < KTOP; ++r) {
                u64 cur = (lane < NW && p < KTOP) ? wco[lane * KTOP + p] : ~0ull;
                u64 bm = wave_min_bc_u64(cur);
                if (cur == bm && bm != ~0ull) p++;
                if (lane == 0) csel[r] = bm;
            }
        }
        __syncthreads();
    }

    // ---- finalize: ks from descending iou sum; scatter selections ----
    if (wid == 0) {
        float tsum = 0.0f;
        #pragma unroll
        for (int r = 0; r < KTOP; ++r) {
            float v = s_iou13[r];
            tsum += (v == NEGINF) ? 0.0f : v;   // descending-order sum (missing = 0, as ref)
        }
        int ks = (int)tsum;
        if (ks < 1) ks = 1;
        if (lane < KTOP && lane < ks) {
            u64 mine = csel[lane];
            if (mine != ~0ull) {
                int idx = (int)(unsigned)(mine & 0xFFFFFFFFull);
                atomicAdd(&count[idx], 1);
                atomicMin(&firstgt[idx], j);
            }
        }
    }
}

// ---------- per-prior finalize; multi-matched priors resolved in-block ----------
__global__ __launch_bounds__(256) void k_assign(
        const float* __restrict__ scores,
        const float4* __restrict__ pbp, const float* __restrict__ gt,
        const void* labels, const int* flag,
        const int* __restrict__ count, const int* __restrict__ firstgt,
        float* __restrict__ out) {
    __shared__ float4 gbox[NGT];
    __shared__ int glab[NGT];
    __shared__ float gcxs[NGT], gcys[NGT], gareas[NGT];
    __shared__ int s_nm;
    __shared__ int s_mlist[256];
    __shared__ u64 red4[4];
    const int tid = threadIdx.x;
    const int is64 = *flag;
    {
        float4 b = ((const float4*)gt)[tid];
        gbox[tid] = b;
        glab[tid] = get_label(labels, tid, is64);
        gcxs[tid] = (b.x + b.z) * 0.5f;
        gcys[tid] = (b.y + b.w) * 0.5f;
        gareas[tid] = (b.z - b.x) * (b.w - b.y);
    }
    if (tid == 0) s_nm = 0;
    __syncthreads();
    const int i = blockIdx.x * 256 + tid;
    const bool act = (i < NPRI);
    if (act) {
        float4 p2 = pbp[2 * i + 1];
        int v = (p2.w != 0.0f) ? 1 : 0;
        int c = count[i];
        float o0 = 0.0f, o1 = -INF_F, o2 = -1.0f;
        if (v && c == 1) {
            int j = firstgt[i];
            float4 pb = pbp[2 * i];
            float areap = (pb.z - pb.x) * (pb.w - pb.y);
            float4 g = gbox[j];
            float iw = fmaxf(fminf(pb.z, g.z) - fmaxf(pb.x, g.x), 0.0f);
            float ih = fmaxf(fminf(pb.w, g.w) - fmaxf(pb.y, g.y), 0.0f);
            float inter = iw * ih;
            float iou = inter / fmaxf(areap + gareas[j] - inter, 1e-6f);
            o0 = (float)(j + 1); o1 = iou; o2 = (float)glab[j];
        } else if (v && c > 1) {
            int p = atomicAdd(&s_nm, 1);
            s_mlist[p] = i;
        }
        out[i] = o0;
        out[NPRI + i] = o1;
        out[2 * NPRI + i] = o2;
    }
    __syncthreads();
    // ---- in-block multi resolution: one GT per thread, block argmin per prior ----
    const int nm = s_nm;
    const int j = tid;
    for (int m = 0; m < nm; ++m) {
        const int ii = s_mlist[m];
        float4 pb = pbp[2 * ii];
        float4 p2 = pbp[2 * ii + 1];
        float areap = (pb.z - pb.x) * (pb.w - pb.y);

        float4 g = gbox[j];
        float iw = fmaxf(fminf(pb.z, g.z) - fmaxf(pb.x, g.x), 0.0f);
        float ih = fmaxf(fminf(pb.w, g.w) - fmaxf(pb.y, g.y), 0.0f);
        float inter = iw * ih;
        float iou = inter / fmaxf(areap + gareas[j] - inter, 1e-6f);
        float dx = p2.x - gcxs[j], dy = p2.y - gcys[j];
        float dist = sqrtf(dx * dx + dy * dy) / p2.z;
        float soft = exp2f((dist - 3.0f) * L10);
        float l = scores[(size_t)ii * NCLS + glab[j]];
        float sig = 1.0f / (1.0f + expf(-l));
        float dd = iou - sig;
        float bce = fmaxf(l, 0.0f) - l * iou + log1pf(expf(-fabsf(l)));
        float cost = bce * (dd * dd) + (-logf(iou + EPS_F) * 3.0f) + soft;

        u64 key = (((u64)__float_as_uint(cost)) << 32) | (unsigned)j;
        u64 v = key;
        #pragma unroll
        for (int off = 32; off > 0; off >>= 1) {
            u64 o = __shfl_down(v, off, 64);
            v = (o < v) ? o : v;
        }
        if ((tid & 63) == 0) red4[tid >> 6] = v;
        __syncthreads();
        u64 best = red4[0];
        #pragma unroll
        for (int q = 1; q < 4; ++q) best = (red4[q] < best) ? red4[q] : best;
        if (key == best) {
            out[ii] = (float)(j + 1);
            out[NPRI + ii] = iou;
            out[2 * NPRI + ii] = (float)glab[j];
        }
        __syncthreads();
    }
}

extern "C" void kernel_launch(void* const* d_in, const int* in_sizes, int n_in,
                              void* d_out, int out_size, void* d_ws, size_t ws_size,
                              hipStream_t stream) {
    const float* scores = (const float*)d_in[0];
    const float* priors = (const float*)d_in[1];
    const float* pboxes = (const float*)d_in[2];
    const float* gt     = (const float*)d_in[3];
    const void*  labels = d_in[4];
    float* out = (float*)d_out;

    char* ws = (char*)d_ws;
    size_t off = 0;
    auto alloc = [&](size_t bytes) { size_t o = off; off = (off + bytes + 255) & ~(size_t)255; return o; };
    int*    flag     = (int*)(ws + alloc(4));
    int*    count    = (int*)(ws + alloc((size_t)NPRI * 4));
    int*    firstgt  = (int*)(ws + alloc((size_t)NPRI * 4));
    float4* pbp      = (float4*)(ws + alloc((size_t)NPRI * 32));
    (void)ws_size;

    hipLaunchKernelGGL(k_prep, dim3(PREP_BLKS), dim3(256), 0, stream,
                       priors, gt, labels, pboxes, pbp, count, firstgt, flag);
    hipLaunchKernelGGL(k_scan, dim3(NGT), dim3(SCN_T), 0, stream,
                       scores, pbp, gt, labels, flag, count, firstgt);
    hipLaunchKernelGGL(k_assign, dim3((NPRI + 255) / 256), dim3(256), 0, stream,
                       scores, pbp, gt, labels, flag, count, firstgt, out);
}

// Round 6
// 145.141 us; speedup vs baseline: 1.0279x; 1.0279x over previous
//
#include <hip/hip_runtime.h>
#include <cstdint>

#define NPRI 33600
#define NGT  256
#define NCLS 80
#define KTOP 13
#define INF_F 1.0e8f
#define EPS_F 1e-7f
#define L10 3.3219280948873623f
#define SCN_T 1024
#define NW   (SCN_T / 64)                   // 16 waves per block
#define CAPI 4096                  // per-GT positive-iou values (full range)
#define CAPC 1024                  // per-GT cost candidates (full range)
#define RFIX 5.5f                  // fixed collect radius (strides); Dmax typically ~4.7
#define NPAD (4 * SCN_T)           // prefetch pad: no clamp math in main loop
#define PREP_BLKS ((NPRI + 255) / 256)
#define NEGINF __int_as_float(0xff800000)

typedef unsigned long long u64;

__device__ __forceinline__ int get_label(const void* p, int j, int is64) {
    if (is64) return (int)((const long long*)p)[j];
    return ((const int*)p)[j];
}

// ---------- wave helpers (reduce + broadcast) ----------
__device__ __forceinline__ float wave_max_bc_f32(float v) {
    #pragma unroll
    for (int off = 32; off > 0; off >>= 1) v = fmaxf(v, __shfl_down(v, off, 64));
    return __int_as_float(__builtin_amdgcn_readfirstlane(__float_as_int(v)));
}
__device__ __forceinline__ u64 wave_min_bc_u64(u64 v) {
    #pragma unroll
    for (int off = 32; off > 0; off >>= 1) { u64 o = __shfl_down(v, off, 64); v = (o < v) ? o : v; }
    unsigned lo = (unsigned)__builtin_amdgcn_readfirstlane((int)(v & 0xffffffffull));
    unsigned hi = (unsigned)__builtin_amdgcn_readfirstlane((int)(v >> 32));
    return (((u64)hi) << 32) | lo;
}
// f32 multiset per-wave top-13: ballot single-lane elimination preserves duplicates
template<int NSL>
__device__ __forceinline__ void wave_merge_max13_f32(float (&l)[NSL], float* dst, int lane) {
    int p = 0;
    for (int r = 0; r < KTOP; ++r) {
        float cur = NEGINF;
        #pragma unroll
        for (int s = 0; s < NSL; ++s) if (s == p) cur = l[NSL - 1 - s];
        float bm = wave_max_bc_f32(cur);
        u64 m = __ballot(cur == bm && bm != NEGINF);
        int first = __ffsll(m) - 1;
        if (lane == first) p++;
        if (lane == 0) dst[r] = bm;
    }
}
// u64 per-wave top-13 min (keys idx-distinct -> single match per round)
template<int NSL>
__device__ __forceinline__ void wave_merge_minN(u64 (&l)[NSL], u64* dst, int lane) {
    int p = 0;
    for (int r = 0; r < KTOP; ++r) {
        u64 cur = ~0ull;
        #pragma unroll
        for (int s = 0; s < NSL; ++s) if (s == p) cur = l[s];
        u64 bm = wave_min_bc_u64(cur);
        if (cur == bm && bm != ~0ull) p++;
        if (lane == 0) dst[r] = bm;
    }
}

// ---------- exact formulas (verbatim: bit-identical selection) ----------
__device__ __forceinline__ float iou_exact(float4 pb, float areap, float gx1, float gy1,
                                           float gx2, float gy2, float areag) {
    float iw = fmaxf(fminf(pb.z, gx2) - fmaxf(pb.x, gx1), 0.0f);
    float ih = fmaxf(fminf(pb.w, gy2) - fmaxf(pb.y, gy1), 0.0f);
    float inter = iw * ih;
    return inter / fmaxf(areap + areag - inter, 1e-6f);
}
__device__ __forceinline__ float cost_exact(float4 p2, float gcx, float gcy,
                                            float l, float iou) {
    float dx = p2.x - gcx, dy = p2.y - gcy;
    float dist = sqrtf(dx * dx + dy * dy) / p2.z;
    float soft = exp2f((dist - 3.0f) * L10);
    float sig = 1.0f / (1.0f + expf(-l));
    float dd = iou - sig;
    float bce = fmaxf(l, 0.0f) - l * iou + log1pf(expf(-fabsf(l)));
    float iouc = -logf(iou + EPS_F) * 3.0f;
    return bce * (dd * dd) + iouc + soft;
}

// ---------- prep: detect int64 + init + valid mask + packed array ----------
// p2 = (px, py, stride, w) where w = valid ? (stride*RFIX)^2*(1+1e-5) : -1
// (identical FP op sequence as the old in-loop radius test, hoisted here)
__global__ __launch_bounds__(256) void k_prep(
        const float* __restrict__ priors, const float* __restrict__ gt,
        const void* labels, const float* __restrict__ pboxes,
        float4* __restrict__ pbp,
        int* count, int* firstgt, int* flag) {
    __shared__ float4 gbox[NGT];
    __shared__ int    gpad[NGT];
    __shared__ int    bad;
    const int tid = threadIdx.x;
    const int b = blockIdx.x;
    if (b == 0 && tid == 0) bad = 0;
    {
        float4 bx = ((const float4*)gt)[tid];
        gbox[tid] = bx;
        gpad[tid] = ((bx.x + bx.y + bx.z + bx.w) > 0.0f) ? 1 : 0;
    }
    __syncthreads();
    if (b == 0 && tid < 128) {
        long long v = ((const long long*)labels)[tid];   // first 1024B: in-bounds either layout
        if (v < 0 || v >= NCLS) atomicOr(&bad, 1);
    }
    int g = b * 256 + tid;
    if (g < NPAD) {   // zero prefetch pad (w=-1 => radius test always false)
        pbp[2 * (NPRI + g)]     = make_float4(0.f, 0.f, 0.f, 0.f);
        pbp[2 * (NPRI + g) + 1] = make_float4(0.f, 0.f, 1.f, -1.0f);
    }
    if (g < NPRI) {
        count[g] = 0; firstgt[g] = NGT;
        float4 pr = ((const float4*)priors)[g];
        float px = pr.x, py = pr.y;
        int v = 0;
        for (int j = 0; j < NGT; ++j) {
            float4 bx = gbox[j];
            float m = fminf(fminf(px - bx.x, py - bx.y), fminf(bx.z - px, bx.w - py));
            if (m > 0.0f && gpad[j]) { v = 1; break; }
        }
        float rad = pr.z * RFIX;
        float w = v ? rad * rad * (1.0f + 1e-5f) : -1.0f;
        pbp[2 * g]     = ((const float4*)pboxes)[g];
        pbp[2 * g + 1] = make_float4(px, py, pr.z, w);
    }
    if (b == 0) {
        __syncthreads();
        if (tid == 0) *flag = bad ? 0 : 1;   // 1 => int64 layout
    }
}

// main-loop step: no bounds check (i <= 32767 < NPRI), unconditional prefetch
// into padded region; rare appends via plain divergent LDS atomics (round-4
// proven; reg-insert was the round-5 VALU regression).
#define STEPM(K, PB, P2) { \
    const int i = i0 + (it + K) * SCN_T; \
    float4 pbc = PB; float4 p2c = P2; \
    const int ip = i + 4 * SCN_T; \
    PB = pbp[2 * ip]; \
    P2 = pbp[2 * ip + 1]; \
    float areap = (pbc.z - pbc.x) * (pbc.w - pbc.y); \
    float iw = fmaxf(fminf(pbc.z, gx2) - fmaxf(pbc.x, gx1), 0.0f); \
    float ih = fmaxf(fminf(pbc.w, gy2) - fmaxf(pbc.y, gy1), 0.0f); \
    float inter = iw * ih; \
    float iou = inter / fmaxf(areap + areag - inter, 1e-6f); \
    if (iou > 0.0f) { \
        int p = atomicAdd(&s_ni, 1); \
        if (p < CAPI) liou[p] = iou; \
    } \
    float dx = p2c.x - gcx, dy = p2c.y - gcy; \
    if (dx * dx + dy * dy <= p2c.w) { \
        int p = atomicAdd(&s_nc, 1); \
        if (p < CAPC) lcost[p] = i; \
    } \
}

// ---------- one block per GT: full-range scan + complete merge + scatter ----------
__global__ __launch_bounds__(SCN_T) void k_scan(
        const float* __restrict__ scores,
        const float4* __restrict__ pbp,
        const float* __restrict__ gt, const void* labels, const int* flag,
        int* count, int* firstgt) {
    const int tid = threadIdx.x, lane = tid & 63, wid = tid >> 6;
    const int j = blockIdx.x;
    const int is64 = *flag;

    const float4 gb = ((const float4*)gt)[j];
    const float gx1 = gb.x, gy1 = gb.y, gx2 = gb.z, gy2 = gb.w;
    const float areag = (gx2 - gx1) * (gy2 - gy1);
    const float gcx = (gx1 + gx2) * 0.5f, gcy = (gy1 + gy2) * 0.5f;
    const int lab = get_label(labels, j, is64);

    __shared__ int s_ni, s_nc, s_mode;
    __shared__ float s_dmax;
    __shared__ float liou[CAPI];
    __shared__ int lcost[CAPC];
    __shared__ float wiof[(NW - 1) * KTOP];   // 15 partial iou lists (waves 1..15)
    __shared__ u64 wco[NW * KTOP];            // mode-2 fallback only
    __shared__ u64 csel[KTOP];
    __shared__ float s_iou13[KTOP];
    if (tid == 0) { s_ni = 0; s_nc = 0; }
    __syncthreads();

    // ---- single pass: 32 guard-free steps (4-deep rotate prefetch) + tail ----
    {
        const int i0 = tid;
        float4 pb0 = pbp[2 * i0],               p20 = pbp[2 * i0 + 1];
        float4 pb1 = pbp[2 * (i0 + SCN_T)],     p21 = pbp[2 * (i0 + SCN_T) + 1];
        float4 pb2 = pbp[2 * (i0 + 2 * SCN_T)], p22 = pbp[2 * (i0 + 2 * SCN_T) + 1];
        float4 pb3 = pbp[2 * (i0 + 3 * SCN_T)], p23 = pbp[2 * (i0 + 3 * SCN_T) + 1];
        for (int it = 0; it < 32; it += 4) {
            STEPM(0, pb0, p20)
            STEPM(1, pb1, p21)
            STEPM(2, pb2, p22)
            STEPM(3, pb3, p23)
        }
        // tail: it = 32 (i in-bounds only for i0 < NPRI - 32768 = 832)
        {
            const int i = i0 + 32 * SCN_T;
            if (i < NPRI) {
                float4 pbc = pb0; float4 p2c = p20;   // prefetched at it=28, K=0
                float areap = (pbc.z - pbc.x) * (pbc.w - pbc.y);
                float iw = fmaxf(fminf(pbc.z, gx2) - fmaxf(pbc.x, gx1), 0.0f);
                float ih = fmaxf(fminf(pbc.w, gy2) - fmaxf(pbc.y, gy1), 0.0f);
                float inter = iw * ih;
                float iou = inter / fmaxf(areap + areag - inter, 1e-6f);
                if (iou > 0.0f) {
                    int p = atomicAdd(&s_ni, 1);
                    if (p < CAPI) liou[p] = iou;
                }
                float dx = p2c.x - gcx, dy = p2c.y - gcy;
                if (dx * dx + dy * dy <= p2c.w) {
                    int p = atomicAdd(&s_nc, 1);
                    if (p < CAPC) lcost[p] = i;
                }
            }
        }
    }
    __syncthreads();
    const int ni = s_ni, nc = s_nc;
    const int ncc = (nc < CAPC) ? nc : CAPC;
    const bool fI = (ni > CAPI);

    // ---- phase 1: wave 0 = cost merge; waves 1..15 = iou partial merges ----
    if (wid == 0) {
        u64 lf[KTOP];
        #pragma unroll
        for (int s = 0; s < KTOP; ++s) lf[s] = ~0ull;
        for (int k = lane; k < ncc; k += 64) {   // <=16 per lane; 13-deep list complete
            int i = lcost[k];
            float4 pb = pbp[2 * i];
            float4 p2 = pbp[2 * i + 1];
            float areap = (pb.z - pb.x) * (pb.w - pb.y);
            float iou = iou_exact(pb, areap, gx1, gy1, gx2, gy2, areag);
            float ec = cost_exact(p2, gcx, gcy, scores[(size_t)i * NCLS + lab], iou);
            u64 ck = (((u64)__float_as_uint(ec)) << 32) | (unsigned)i;
            if (ck < lf[KTOP - 1]) {
                lf[KTOP - 1] = ck;
                #pragma unroll
                for (int s = KTOP - 1; s > 0; --s)
                    if (lf[s] < lf[s - 1]) { u64 t = lf[s]; lf[s] = lf[s - 1]; lf[s - 1] = t; }
            }
        }
        wave_merge_minN<KTOP>(lf, csel, lane);
        if (lane == 0) {
            u64 tk = csel[KTOP - 1];
            int mode; float dmax = 0.0f;
            if (tk == ~0ull) mode = 2;               // <13 candidates in RFIX ball
            else {
                float tau = __uint_as_float((unsigned)(tk >> 32));
                if (!(tau < 9.0e7f)) mode = 2;       // INF-ambiguity zone
                else {
                    dmax = 3.0f + __log2f(tau + 1e-5f) * (1.0f / L10) + 4e-3f;
                    mode = (dmax > RFIX || nc > CAPC) ? 1 : 0;
                }
            }
            s_mode = mode; s_dmax = dmax;
        }
    } else if (!fI) {
        float lf[KTOP];
        #pragma unroll
        for (int s = 0; s < KTOP; ++s) lf[s] = NEGINF;
        int nn = (ni < CAPI) ? ni : CAPI;
        for (int k = (wid - 1) * 64 + lane; k < nn; k += 64 * (NW - 1)) {  // ~4-5 per lane
            float v = liou[k];
            if (v > lf[0]) {
                lf[0] = v;
                #pragma unroll
                for (int s = 0; s < KTOP - 1; ++s)
                    if (lf[s] > lf[s + 1]) { float t = lf[s]; lf[s] = lf[s + 1]; lf[s + 1] = t; }
            }
        }
        wave_merge_max13_f32<KTOP>(lf, &wiof[(wid - 1) * KTOP], lane);
    }
    __syncthreads();

    if (fI) {   // rare: iou list overflowed -> exact full rescan by waves 1..15
        if (wid > 0) {
            float lf[KTOP];
            #pragma unroll
            for (int s = 0; s < KTOP; ++s) lf[s] = NEGINF;
            for (int i = (wid - 1) * 64 + lane; i < NPRI; i += 64 * (NW - 1)) {
                float4 pb = pbp[2 * i];
                float areap = (pb.z - pb.x) * (pb.w - pb.y);
                float iou = iou_exact(pb, areap, gx1, gy1, gx2, gy2, areag);
                if (iou > 0.0f && iou > lf[0]) {
                    lf[0] = iou;
                    #pragma unroll
                    for (int s = 0; s < KTOP - 1; ++s)
                        if (lf[s] > lf[s + 1]) { float t = lf[s]; lf[s] = lf[s + 1]; lf[s + 1] = t; }
                }
            }
            wave_merge_max13_f32<KTOP>(lf, &wiof[(wid - 1) * KTOP], lane);
        }
        __syncthreads();
    }

    // ---- cross-merge the 15 iou lists -> s_iou13 (descending, multiset) ----
    if (wid == 0) {
        int p = 0;
        for (int r = 0; r < KTOP; ++r) {
            float cur = (lane < NW - 1 && p < KTOP) ? wiof[lane * KTOP + p] : NEGINF;
            float bm = wave_max_bc_f32(cur);
            u64 m = __ballot(cur == bm && bm != NEGINF);
            int first = __ffsll(m) - 1;
            if (lane == first) p++;
            if (lane == 0) s_iou13[r] = bm;
        }
    }

    int mode = s_mode;
    if (mode == 1) {   // re-collect at the sound radius Dmax' (rare)
        const float dmax = s_dmax;
        if (tid == 0) s_nc = 0;
        __syncthreads();
        for (int i = tid; i < NPRI; i += SCN_T) {
            float4 p2 = pbp[2 * i + 1];
            if (p2.w > 0.0f) {
                float dx = p2.x - gcx, dy = p2.y - gcy;
                float rad = p2.z * dmax;
                if (dx * dx + dy * dy <= rad * rad * (1.0f + 1e-5f)) {
                    int p = atomicAdd(&s_nc, 1);
                    if (p < CAPC) lcost[p] = i;
                }
            }
        }
        __syncthreads();
        int nc2 = s_nc;
        if (nc2 <= CAPC) {
            if (wid == 0) {
                u64 lf[KTOP];
                #pragma unroll
                for (int s = 0; s < KTOP; ++s) lf[s] = ~0ull;
                for (int k = lane; k < nc2; k += 64) {
                    int i = lcost[k];
                    float4 pb = pbp[2 * i];
                    float4 p2 = pbp[2 * i + 1];
                    float areap = (pb.z - pb.x) * (pb.w - pb.y);
                    float iou = iou_exact(pb, areap, gx1, gy1, gx2, gy2, areag);
                    float ec = cost_exact(p2, gcx, gcy, scores[(size_t)i * NCLS + lab], iou);
                    u64 ck = (((u64)__float_as_uint(ec)) << 32) | (unsigned)i;
                    if (ck < lf[KTOP - 1]) {
                        lf[KTOP - 1] = ck;
                        #pragma unroll
                        for (int s = KTOP - 1; s > 0; --s)
                            if (lf[s] < lf[s - 1]) { u64 t = lf[s]; lf[s] = lf[s - 1]; lf[s - 1] = t; }
                    }
                }
                wave_merge_minN<KTOP>(lf, csel, lane);
            }
        } else {
            mode = 2;   // uniform (s_nc shared)
        }
        __syncthreads();
    }
    if (mode == 2) {   // exact full scan (correctness net)
        u64 lf[KTOP];
        #pragma unroll
        for (int s = 0; s < KTOP; ++s) lf[s] = ~0ull;
        for (int i = tid; i < NPRI; i += SCN_T) {
            float4 pb = pbp[2 * i];
            float4 p2 = pbp[2 * i + 1];
            float areap = (pb.z - pb.x) * (pb.w - pb.y);
            float iou = iou_exact(pb, areap, gx1, gy1, gx2, gy2, areag);
            float ec = INF_F;
            if (p2.w > 0.0f) ec = cost_exact(p2, gcx, gcy, scores[(size_t)i * NCLS + lab], iou);
            u64 k2 = (((u64)__float_as_uint(ec)) << 32) | (unsigned)i;
            if (k2 < lf[KTOP - 1]) {
                lf[KTOP - 1] = k2;
                #pragma unroll
                for (int s = KTOP - 1; s > 0; --s)
                    if (lf[s] < lf[s - 1]) { u64 t = lf[s]; lf[s] = lf[s - 1]; lf[s - 1] = t; }
            }
        }
        wave_merge_minN<KTOP>(lf, &wco[wid * KTOP], lane);
        __syncthreads();
        if (wid == 0) {
            int p = 0;
            for (int r = 0; r < KTOP; ++r) {
                u64 cur = (lane < NW && p < KTOP) ? wco[lane * KTOP + p] : ~0ull;
                u64 bm = wave_min_bc_u64(cur);
                if (cur == bm && bm != ~0ull) p++;
                if (lane == 0) csel[r] = bm;
            }
        }
        __syncthreads();
    }

    // ---- finalize: ks from descending iou sum; scatter selections ----
    __syncthreads();
    if (wid == 0) {
        float tsum = 0.0f;
        #pragma unroll
        for (int r = 0; r < KTOP; ++r) {
            float v = s_iou13[r];
            tsum += (v == NEGINF) ? 0.0f : v;   // descending-order sum (missing = 0, as ref)
        }
        int ks = (int)tsum;
        if (ks < 1) ks = 1;
        if (lane < KTOP && lane < ks) {
            u64 mine = csel[lane];
            if (mine != ~0ull) {
                int idx = (int)(unsigned)(mine & 0xFFFFFFFFull);
                atomicAdd(&count[idx], 1);
                atomicMin(&firstgt[idx], j);
            }
        }
    }
}

// ---------- per-prior finalize; multi-matched priors resolved in-block ----------
__global__ __launch_bounds__(256) void k_assign(
        const float* __restrict__ scores,
        const float4* __restrict__ pbp, const float* __restrict__ gt,
        const void* labels, const int* flag,
        const int* __restrict__ count, const int* __restrict__ firstgt,
        float* __restrict__ out) {
    __shared__ float4 gbox[NGT];
    __shared__ int glab[NGT];
    __shared__ float gcxs[NGT], gcys[NGT], gareas[NGT];
    __shared__ int s_nm;
    __shared__ int s_mlist[256];
    __shared__ u64 red4[4];
    const int tid = threadIdx.x;
    const int is64 = *flag;
    {
        float4 b = ((const float4*)gt)[tid];
        gbox[tid] = b;
        glab[tid] = get_label(labels, tid, is64);
        gcxs[tid] = (b.x + b.z) * 0.5f;
        gcys[tid] = (b.y + b.w) * 0.5f;
        gareas[tid] = (b.z - b.x) * (b.w - b.y);
    }
    if (tid == 0) s_nm = 0;
    __syncthreads();
    const int i = blockIdx.x * 256 + tid;
    const bool act = (i < NPRI);
    if (act) {
        float4 p2 = pbp[2 * i + 1];
        int v = (p2.w > 0.0f) ? 1 : 0;
        int c = count[i];
        float o0 = 0.0f, o1 = -INF_F, o2 = -1.0f;
        if (v && c == 1) {
            int j = firstgt[i];
            float4 pb = pbp[2 * i];
            float areap = (pb.z - pb.x) * (pb.w - pb.y);
            float4 g = gbox[j];
            float iw = fmaxf(fminf(pb.z, g.z) - fmaxf(pb.x, g.x), 0.0f);
            float ih = fmaxf(fminf(pb.w, g.w) - fmaxf(pb.y, g.y), 0.0f);
            float inter = iw * ih;
            float iou = inter / fmaxf(areap + gareas[j] - inter, 1e-6f);
            o0 = (float)(j + 1); o1 = iou; o2 = (float)glab[j];
        } else if (v && c > 1) {
            int p = atomicAdd(&s_nm, 1);
            s_mlist[p] = i;
        }
        out[i] = o0;
        out[NPRI + i] = o1;
        out[2 * NPRI + i] = o2;
    }
    __syncthreads();
    // ---- in-block multi resolution: one GT per thread, block argmin per prior ----
    const int nm = s_nm;
    const int j = tid;
    for (int m = 0; m < nm; ++m) {
        const int ii = s_mlist[m];
        float4 pb = pbp[2 * ii];
        float4 p2 = pbp[2 * ii + 1];
        float areap = (pb.z - pb.x) * (pb.w - pb.y);

        float4 g = gbox[j];
        float iw = fmaxf(fminf(pb.z, g.z) - fmaxf(pb.x, g.x), 0.0f);
        float ih = fmaxf(fminf(pb.w, g.w) - fmaxf(pb.y, g.y), 0.0f);
        float inter = iw * ih;
        float iou = inter / fmaxf(areap + gareas[j] - inter, 1e-6f);
        float dx = p2.x - gcxs[j], dy = p2.y - gcys[j];
        float dist = sqrtf(dx * dx + dy * dy) / p2.z;
        float soft = exp2f((dist - 3.0f) * L10);
        float l = scores[(size_t)ii * NCLS + glab[j]];
        float sig = 1.0f / (1.0f + expf(-l));
        float dd = iou - sig;
        float bce = fmaxf(l, 0.0f) - l * iou + log1pf(expf(-fabsf(l)));
        float cost = bce * (dd * dd) + (-logf(iou + EPS_F) * 3.0f) + soft;

        u64 key = (((u64)__float_as_uint(cost)) << 32) | (unsigned)j;
        u64 v = key;
        #pragma unroll
        for (int off = 32; off > 0; off >>= 1) {
            u64 o = __shfl_down(v, off, 64);
            v = (o < v) ? o : v;
        }
        if ((tid & 63) == 0) red4[tid >> 6] = v;
        __syncthreads();
        u64 best = red4[0];
        #pragma unroll
        for (int q = 1; q < 4; ++q) best = (red4[q] < best) ? red4[q] : best;
        if (key == best) {
            out[ii] = (float)(j + 1);
            out[NPRI + ii] = iou;
            out[2 * NPRI + ii] = (float)glab[j];
        }
        __syncthreads();
    }
}

extern "C" void kernel_launch(void* const* d_in, const int* in_sizes, int n_in,
                              void* d_out, int out_size, void* d_ws, size_t ws_size,
                              hipStream_t stream) {
    const float* scores = (const float*)d_in[0];
    const float* priors = (const float*)d_in[1];
    const float* pboxes = (const float*)d_in[2];
    const float* gt     = (const float*)d_in[3];
    const void*  labels = d_in[4];
    float* out = (float*)d_out;

    char* ws = (char*)d_ws;
    size_t off = 0;
    auto alloc = [&](size_t bytes) { size_t o = off; off = (off + bytes + 255) & ~(size_t)255; return o; };
    int*    flag     = (int*)(ws + alloc(4));
    int*    count    = (int*)(ws + alloc((size_t)NPRI * 4));
    int*    firstgt  = (int*)(ws + alloc((size_t)NPRI * 4));
    float4* pbp      = (float4*)(ws + alloc((size_t)(NPRI + NPAD) * 32));
    (void)ws_size;

    hipLaunchKernelGGL(k_prep, dim3(PREP_BLKS), dim3(256), 0, stream,
                       priors, gt, labels, pboxes, pbp, count, firstgt, flag);
    hipLaunchKernelGGL(k_scan, dim3(NGT), dim3(SCN_T), 0, stream,
                       scores, pbp, gt, labels, flag, count, firstgt);
    hipLaunchKernelGGL(k_assign, dim3((NPRI + 255) / 256), dim3(256), 0, stream,
                       scores, pbp, gt, labels, flag, count, firstgt, out);
}

// Round 7
// 144.578 us; speedup vs baseline: 1.0319x; 1.0039x over previous
//
#include <hip/hip_runtime.h>
#include <cstdint>

#define NPRI 33600
#define NGT  256
#define NCLS 80
#define KTOP 13
#define INF_F 1.0e8f
#define EPS_F 1e-7f
#define L10 3.3219280948873623f
#define SLC  4
#define SLEN (NPRI / SLC)          // 8400
#define SCN_T 512
#define NW8 (SCN_T / 64)           // 8 waves per block
#define NIT  ((SLEN + SCN_T - 1) / SCN_T)   // 17
#define CAPI 1536                  // per-slice positive-iou values
#define CAPC 512                   // per-slice cost candidates
#define RFIX 5.5f                  // fixed collect radius (strides)
#define PREP_BLKS ((NPRI + 255) / 256)
#define NEGINF __int_as_float(0xff800000)

typedef unsigned long long u64;

__device__ __forceinline__ int get_label(const void* p, int j, int is64) {
    if (is64) return (int)((const long long*)p)[j];
    return ((const int*)p)[j];
}

// ---------- agent-coherent (cross-XCD) scalar access: sc1 ops, NO L2 flush ----------
__device__ __forceinline__ void st_agent_f32(float* p, float v) {
    __hip_atomic_store(p, v, __ATOMIC_RELAXED, __HIP_MEMORY_SCOPE_AGENT);
}
__device__ __forceinline__ void st_agent_u64(u64* p, u64 v) {
    __hip_atomic_store(p, v, __ATOMIC_RELAXED, __HIP_MEMORY_SCOPE_AGENT);
}
__device__ __forceinline__ float ld_agent_f32(const float* p) {
    return __hip_atomic_load(p, __ATOMIC_RELAXED, __HIP_MEMORY_SCOPE_AGENT);
}
__device__ __forceinline__ u64 ld_agent_u64(const u64* p) {
    return __hip_atomic_load(p, __ATOMIC_RELAXED, __HIP_MEMORY_SCOPE_AGENT);
}

// ---------- wave helpers (reduce + broadcast) ----------
__device__ __forceinline__ float wave_max_bc_f32(float v) {
    #pragma unroll
    for (int off = 32; off > 0; off >>= 1) v = fmaxf(v, __shfl_down(v, off, 64));
    return __int_as_float(__builtin_amdgcn_readfirstlane(__float_as_int(v)));
}
__device__ __forceinline__ u64 wave_min_bc_u64(u64 v) {
    #pragma unroll
    for (int off = 32; off > 0; off >>= 1) { u64 o = __shfl_down(v, off, 64); v = (o < v) ? o : v; }
    unsigned lo = (unsigned)__builtin_amdgcn_readfirstlane((int)(v & 0xffffffffull));
    unsigned hi = (unsigned)__builtin_amdgcn_readfirstlane((int)(v >> 32));
    return (((u64)hi) << 32) | lo;
}
// f32 multiset per-wave top-13: ballot single-lane elimination preserves duplicates
template<int NSL, bool AGENT>
__device__ __forceinline__ void wave_merge_max13_f32(float (&l)[NSL], float* dst, int lane) {
    int p = 0;
    for (int r = 0; r < KTOP; ++r) {
        float cur = NEGINF;
        #pragma unroll
        for (int s = 0; s < NSL; ++s) if (s == p) cur = l[NSL - 1 - s];
        float bm = wave_max_bc_f32(cur);
        u64 m = __ballot(cur == bm && bm != NEGINF);
        int first = __ffsll(m) - 1;
        if (lane == first) p++;
        if (lane == 0) {
            if (AGENT) st_agent_f32(dst + r, bm);
            else dst[r] = bm;
        }
    }
}
// u64 per-wave top-13 min (keys idx-distinct -> single match per round)
template<int NSL>
__device__ __forceinline__ void wave_merge_minN(u64 (&l)[NSL], u64* dst, int lane) {
    int p = 0;
    for (int r = 0; r < KTOP; ++r) {
        u64 cur = ~0ull;
        #pragma unroll
        for (int s = 0; s < NSL; ++s) if (s == p) cur = l[s];
        u64 bm = wave_min_bc_u64(cur);
        if (cur == bm && bm != ~0ull) p++;
        if (lane == 0) dst[r] = bm;
    }
}

// ---------- exact formulas (verbatim: bit-identical selection) ----------
__device__ __forceinline__ float iou_exact(float4 pb, float areap, float gx1, float gy1,
                                           float gx2, float gy2, float areag) {
    float iw = fmaxf(fminf(pb.z, gx2) - fmaxf(pb.x, gx1), 0.0f);
    float ih = fmaxf(fminf(pb.w, gy2) - fmaxf(pb.y, gy1), 0.0f);
    float inter = iw * ih;
    return inter / fmaxf(areap + areag - inter, 1e-6f);
}
__device__ __forceinline__ float cost_exact(float4 p2, float gcx, float gcy,
                                            float l, float iou) {
    float dx = p2.x - gcx, dy = p2.y - gcy;
    float dist = sqrtf(dx * dx + dy * dy) / p2.z;
    float soft = exp2f((dist - 3.0f) * L10);
    float sig = 1.0f / (1.0f + expf(-l));
    float dd = iou - sig;
    float bce = fmaxf(l, 0.0f) - l * iou + log1pf(expf(-fabsf(l)));
    float iouc = -logf(iou + EPS_F) * 3.0f;
    return bce * (dd * dd) + iouc + soft;
}

// ---------- prep: detect int64 + init + valid mask + packed array ----------
// p2 = (px, py, stride, w) where w = valid ? (stride*RFIX)^2*(1+1e-5) : -1
__global__ __launch_bounds__(256) void k_prep(
        const float* __restrict__ priors, const float* __restrict__ gt,
        const void* labels, const float* __restrict__ pboxes,
        float4* __restrict__ pbp,
        int* count, int* firstgt, int* flag, int* slice_done) {
    __shared__ float4 gbox[NGT];
    __shared__ int    gpad[NGT];
    __shared__ int    bad;
    const int tid = threadIdx.x;
    const int b = blockIdx.x;
    if (b == 0 && tid == 0) bad = 0;
    if (b == 0) slice_done[tid] = 0;     // NGT == 256 == blockDim
    {
        float4 bx = ((const float4*)gt)[tid];
        gbox[tid] = bx;
        gpad[tid] = ((bx.x + bx.y + bx.z + bx.w) > 0.0f) ? 1 : 0;
    }
    __syncthreads();
    if (b == 0 && tid < 128) {
        long long v = ((const long long*)labels)[tid];   // first 1024B: in-bounds either layout
        if (v < 0 || v >= NCLS) atomicOr(&bad, 1);
    }
    int g = b * 256 + tid;
    if (g < NPRI) {
        count[g] = 0; firstgt[g] = NGT;
        float4 pr = ((const float4*)priors)[g];
        float px = pr.x, py = pr.y;
        int v = 0;
        for (int j = 0; j < NGT; ++j) {
            float4 bx = gbox[j];
            float m = fminf(fminf(px - bx.x, py - bx.y), fminf(bx.z - px, bx.w - py));
            if (m > 0.0f && gpad[j]) { v = 1; break; }
        }
        float rad = pr.z * RFIX;
        float w = v ? rad * rad * (1.0f + 1e-5f) : -1.0f;
        pbp[2 * g]     = ((const float4*)pboxes)[g];
        pbp[2 * g + 1] = make_float4(px, py, pr.z, w);
    }
    if (b == 0) {
        __syncthreads();
        if (tid == 0) *flag = bad ? 0 : 1;   // 1 => int64 layout
    }
}

// ---------- 4 slices x 512 thr per GT (4 blocks/CU, 32 waves/CU); plain LDS
// atomic appends (no ballot chains); sc1 last-block merge (no L2 flush) ----------
__global__ __launch_bounds__(SCN_T, 8) void k_scan(
        const float* __restrict__ scores,
        const float4* __restrict__ pbp,
        const float* __restrict__ gt, const void* labels, const int* flag,
        float* __restrict__ part_iou, u64* __restrict__ part_cost,
        int* count, int* firstgt, int* slice_done) {
    const int tid = threadIdx.x, lane = tid & 63, wid = tid >> 6;
    const int j = blockIdx.x, slice = blockIdx.y;
    const int base = slice * SLEN;
    const int lim = base + SLEN;
    const int is64 = *flag;

    const float4 gb = ((const float4*)gt)[j];
    const float gx1 = gb.x, gy1 = gb.y, gx2 = gb.z, gy2 = gb.w;
    const float areag = (gx2 - gx1) * (gy2 - gy1);
    const float gcx = (gx1 + gx2) * 0.5f, gcy = (gy1 + gy2) * 0.5f;
    const int lab = get_label(labels, j, is64);

    __shared__ int s_ni, s_nc, s_mode, s_last;
    __shared__ float s_dmax;
    __shared__ float liou[CAPI];
    __shared__ int lcost[CAPC];
    __shared__ float wiof[NW8 * KTOP];   // fI fallback only
    __shared__ u64 wco[NW8 * KTOP];      // mode-2 fallback only
    __shared__ u64 csel[KTOP];
    if (tid == 0) { s_ni = 0; s_nc = 0; }
    __syncthreads();

    // ---- single pass, uniform 17-iter trip, 2-deep prefetch, plain atomics ----
    {
        const int i0 = base + tid;               // always < lim (SLEN > SCN_T)
        int ia1 = i0 + SCN_T;                    // < lim (tid+512 <= 1023 < 8400)
        float4 pb_c = pbp[2 * i0],  p2_c = pbp[2 * i0 + 1];
        float4 pb_n = pbp[2 * ia1], p2_n = pbp[2 * ia1 + 1];
        for (int it = 0; it < NIT; ++it) {
            int i = i0 + it * SCN_T;
            int ipre = i + 2 * SCN_T;
            int ic = (ipre < lim) ? ipre : i0;   // clamped prefetch address (always valid)
            float4 pb_p = pbp[2 * ic];
            float4 p2_p = pbp[2 * ic + 1];       // two loads in flight during compute

            if (i < lim) {
                float areap = (pb_c.z - pb_c.x) * (pb_c.w - pb_c.y);
                float iw = fmaxf(fminf(pb_c.z, gx2) - fmaxf(pb_c.x, gx1), 0.0f);
                float ih = fmaxf(fminf(pb_c.w, gy2) - fmaxf(pb_c.y, gy1), 0.0f);
                float inter = iw * ih;
                float iou = inter / fmaxf(areap + areag - inter, 1e-6f);   // exact
                if (iou > 0.0f) {
                    int p = atomicAdd(&s_ni, 1);
                    if (p < CAPI) liou[p] = iou;
                }
                float dx = p2_c.x - gcx, dy = p2_c.y - gcy;
                if (dx * dx + dy * dy <= p2_c.w) {
                    int p = atomicAdd(&s_nc, 1);
                    if (p < CAPC) lcost[p] = i;
                }
            }
            pb_c = pb_n; p2_c = p2_n;
            pb_n = pb_p; p2_n = p2_p;
        }
    }
    __syncthreads();
    const int ni = s_ni, nc = s_nc;
    const int ncc = (nc < CAPC) ? nc : CAPC;
    const bool fI = (ni > CAPI);

    // ---- parallel single-wave merges: wave 0 = cost, wave 1 = iou ----
    if (wid == 0) {
        u64 lf[KTOP];
        #pragma unroll
        for (int s = 0; s < KTOP; ++s) lf[s] = ~0ull;
        for (int k = lane; k < ncc; k += 64) {   // <=8 per lane; 13-deep list complete
            int i = lcost[k];
            float4 pb = pbp[2 * i];
            float4 p2 = pbp[2 * i + 1];
            float areap = (pb.z - pb.x) * (pb.w - pb.y);
            float iou = iou_exact(pb, areap, gx1, gy1, gx2, gy2, areag);
            float ec = cost_exact(p2, gcx, gcy, scores[(size_t)i * NCLS + lab], iou);
            u64 ck = (((u64)__float_as_uint(ec)) << 32) | (unsigned)i;
            if (ck < lf[KTOP - 1]) {
                lf[KTOP - 1] = ck;
                #pragma unroll
                for (int s = KTOP - 1; s > 0; --s)
                    if (lf[s] < lf[s - 1]) { u64 t = lf[s]; lf[s] = lf[s - 1]; lf[s - 1] = t; }
            }
        }
        wave_merge_minN<KTOP>(lf, csel, lane);
        if (lane == 0) {
            u64 tk = csel[KTOP - 1];
            int mode; float dmax = 0.0f;
            if (tk == ~0ull) mode = 2;               // <13 candidates in RFIX ball
            else {
                float tau = __uint_as_float((unsigned)(tk >> 32));
                if (!(tau < 9.0e7f)) mode = 2;       // INF-ambiguity zone
                else {
                    dmax = 3.0f + __log2f(tau + 1e-5f) * (1.0f / L10) + 4e-3f;
                    mode = (dmax > RFIX || nc > CAPC) ? 1 : 0;
                }
            }
            s_mode = mode; s_dmax = dmax;
        }
    } else if (wid == 1 && !fI) {
        float lf[KTOP];
        #pragma unroll
        for (int s = 0; s < KTOP; ++s) lf[s] = NEGINF;
        int nn = (ni < CAPI) ? ni : CAPI;
        for (int k = lane; k < nn; k += 64) {    // <=24 per lane; 13-deep retains any lane's top-13
            float v = liou[k];
            if (v > lf[0]) {
                lf[0] = v;
                #pragma unroll
                for (int s = 0; s < KTOP - 1; ++s)
                    if (lf[s] > lf[s + 1]) { float t = lf[s]; lf[s] = lf[s + 1]; lf[s + 1] = t; }
            }
        }
        wave_merge_max13_f32<KTOP, true>(lf, part_iou + ((size_t)j * SLC + slice) * KTOP, lane);
    }
    __syncthreads();

    if (fI) {   // rare: iou list overflowed -> exact full-slice scan (two-stage merge)
        float lf[KTOP];
        #pragma unroll
        for (int s = 0; s < KTOP; ++s) lf[s] = NEGINF;
        for (int i = base + tid; i < lim; i += SCN_T) {
            float4 pb = pbp[2 * i];
            float areap = (pb.z - pb.x) * (pb.w - pb.y);
            float iou = iou_exact(pb, areap, gx1, gy1, gx2, gy2, areag);
            if (iou > 0.0f && iou > lf[0]) {
                lf[0] = iou;
                #pragma unroll
                for (int s = 0; s < KTOP - 1; ++s)
                    if (lf[s] > lf[s + 1]) { float t = lf[s]; lf[s] = lf[s + 1]; lf[s + 1] = t; }
            }
        }
        wave_merge_max13_f32<KTOP, false>(lf, &wiof[wid * KTOP], lane);
        __syncthreads();
        if (wid == 0) {
            float* dpi = part_iou + ((size_t)j * SLC + slice) * KTOP;
            int p = 0;
            for (int r = 0; r < KTOP; ++r) {
                float cur = (lane < NW8 && p < KTOP) ? wiof[lane * KTOP + p] : NEGINF;
                float bm = wave_max_bc_f32(cur);
                u64 m = __ballot(cur == bm && bm != NEGINF);
                int first = __ffsll(m) - 1;
                if (lane == first) p++;
                if (lane == 0) st_agent_f32(dpi + r, bm);
            }
        }
        __syncthreads();
    }

    int mode = s_mode;
    if (mode == 1) {   // re-collect at the sound radius Dmax' (rare)
        const float dmax = s_dmax;
        if (tid == 0) s_nc = 0;
        __syncthreads();
        for (int i = base + tid; i < lim; i += SCN_T) {
            float4 p2 = pbp[2 * i + 1];
            if (p2.w > 0.0f) {
                float dx = p2.x - gcx, dy = p2.y - gcy;
                float rad = p2.z * dmax;
                if (dx * dx + dy * dy <= rad * rad * (1.0f + 1e-5f)) {
                    int p = atomicAdd(&s_nc, 1);
                    if (p < CAPC) lcost[p] = i;
                }
            }
        }
        __syncthreads();
        int nc2 = s_nc;
        if (nc2 <= CAPC) {
            if (wid == 0) {
                u64 lf[KTOP];
                #pragma unroll
                for (int s = 0; s < KTOP; ++s) lf[s] = ~0ull;
                for (int k = lane; k < nc2; k += 64) {
                    int i = lcost[k];
                    float4 pb = pbp[2 * i];
                    float4 p2 = pbp[2 * i + 1];
                    float areap = (pb.z - pb.x) * (pb.w - pb.y);
                    float iou = iou_exact(pb, areap, gx1, gy1, gx2, gy2, areag);
                    float ec = cost_exact(p2, gcx, gcy, scores[(size_t)i * NCLS + lab], iou);
                    u64 ck = (((u64)__float_as_uint(ec)) << 32) | (unsigned)i;
                    if (ck < lf[KTOP - 1]) {
                        lf[KTOP - 1] = ck;
                        #pragma unroll
                        for (int s = KTOP - 1; s > 0; --s)
                            if (lf[s] < lf[s - 1]) { u64 t = lf[s]; lf[s] = lf[s - 1]; lf[s - 1] = t; }
                    }
                }
                wave_merge_minN<KTOP>(lf, csel, lane);
            }
        } else {
            mode = 2;   // uniform (s_nc shared)
        }
        __syncthreads();
    }
    if (mode == 2) {   // exact full slice scan (correctness net)
        u64 lf[KTOP];
        #pragma unroll
        for (int s = 0; s < KTOP; ++s) lf[s] = ~0ull;
        for (int i = base + tid; i < lim; i += SCN_T) {
            float4 pb = pbp[2 * i];
            float4 p2 = pbp[2 * i + 1];
            float areap = (pb.z - pb.x) * (pb.w - pb.y);
            float iou = iou_exact(pb, areap, gx1, gy1, gx2, gy2, areag);
            float ec = INF_F;
            if (p2.w > 0.0f) ec = cost_exact(p2, gcx, gcy, scores[(size_t)i * NCLS + lab], iou);
            u64 k2 = (((u64)__float_as_uint(ec)) << 32) | (unsigned)i;
            if (k2 < lf[KTOP - 1]) {
                lf[KTOP - 1] = k2;
                #pragma unroll
                for (int s = KTOP - 1; s > 0; --s)
                    if (lf[s] < lf[s - 1]) { u64 t = lf[s]; lf[s] = lf[s - 1]; lf[s - 1] = t; }
            }
        }
        wave_merge_minN<KTOP>(lf, &wco[wid * KTOP], lane);
        __syncthreads();
        if (wid == 0) {
            int p = 0;
            for (int r = 0; r < KTOP; ++r) {
                u64 cur = (lane < NW8 && p < KTOP) ? wco[lane * KTOP + p] : ~0ull;
                u64 bm = wave_min_bc_u64(cur);
                if (cur == bm && bm != ~0ull) p++;
                if (lane == 0) csel[r] = bm;
            }
        }
        __syncthreads();
    }
    if (tid < KTOP) {
        u64* dpc = part_cost + ((size_t)j * SLC + slice) * KTOP;
        st_agent_u64(dpc + tid, csel[tid]);
    }

    // ---- fused per-GT merge: last-finishing slice merges all SLC slices.
    // All part stores above are sc1 (agent-coherent); __syncthreads drains
    // vmcnt(0) before its barrier -> visible before the flag bump. NO
    // __threadfence (full-L2 wbl2/inv) anywhere — that was the round-1 regression.
    asm volatile("s_waitcnt vmcnt(0)" ::: "memory");
    __syncthreads();
    if (tid == 0) s_last = (atomicAdd(&slice_done[j], 1) == SLC - 1) ? 1 : 0;
    __syncthreads();
    if (s_last && wid == 0) {
        const int l = lane;
        float vi = (l < SLC * KTOP) ? ld_agent_f32(part_iou + (size_t)j * SLC * KTOP + l) : NEGINF;
        float tsum = 0.0f;
        for (int r = 0; r < KTOP; ++r) {
            float bm = wave_max_bc_f32(vi);
            u64 mmask = __ballot(vi == bm && bm != NEGINF);
            int first = __ffsll(mmask) - 1;
            if (l == first) vi = NEGINF;
            tsum += (bm == NEGINF) ? 0.0f : bm;   // descending-order sum (missing = 0, as ref)
        }
        int ks = (int)tsum;
        if (ks < 1) ks = 1;
        u64 kc = (l < SLC * KTOP) ? ld_agent_u64(part_cost + (size_t)j * SLC * KTOP + l) : ~0ull;
        u64 mine = ~0ull;
        for (int r = 0; r < KTOP; ++r) {
            u64 bm = wave_min_bc_u64(kc);
            if (kc == bm && bm != ~0ull) kc = ~0ull;
            if (l == r) mine = bm;
        }
        if (l < KTOP && l < ks && mine != ~0ull) {
            int idx = (int)(unsigned)(mine & 0xFFFFFFFFull);
            atomicAdd(&count[idx], 1);
            atomicMin(&firstgt[idx], j);
        }
    }
}

// ---------- per-prior finalize; multi-matched priors resolved in-block ----------
__global__ __launch_bounds__(256) void k_assign(
        const float* __restrict__ scores,
        const float4* __restrict__ pbp, const float* __restrict__ gt,
        const void* labels, const int* flag,
        const int* __restrict__ count, const int* __restrict__ firstgt,
        float* __restrict__ out) {
    __shared__ float4 gbox[NGT];
    __shared__ int glab[NGT];
    __shared__ float gcxs[NGT], gcys[NGT], gareas[NGT];
    __shared__ int s_nm;
    __shared__ int s_mlist[256];
    __shared__ u64 red4[4];
    const int tid = threadIdx.x;
    const int is64 = *flag;
    {
        float4 b = ((const float4*)gt)[tid];
        gbox[tid] = b;
        glab[tid] = get_label(labels, tid, is64);
        gcxs[tid] = (b.x + b.z) * 0.5f;
        gcys[tid] = (b.y + b.w) * 0.5f;
        gareas[tid] = (b.z - b.x) * (b.w - b.y);
    }
    if (tid == 0) s_nm = 0;
    __syncthreads();
    const int i = blockIdx.x * 256 + tid;
    const bool act = (i < NPRI);
    if (act) {
        float4 p2 = pbp[2 * i + 1];
        int v = (p2.w > 0.0f) ? 1 : 0;
        int c = count[i];
        float o0 = 0.0f, o1 = -INF_F, o2 = -1.0f;
        if (v && c == 1) {
            int j = firstgt[i];
            float4 pb = pbp[2 * i];
            float areap = (pb.z - pb.x) * (pb.w - pb.y);
            float4 g = gbox[j];
            float iw = fmaxf(fminf(pb.z, g.z) - fmaxf(pb.x, g.x), 0.0f);
            float ih = fmaxf(fminf(pb.w, g.w) - fmaxf(pb.y, g.y), 0.0f);
            float inter = iw * ih;
            float iou = inter / fmaxf(areap + gareas[j] - inter, 1e-6f);
            o0 = (float)(j + 1); o1 = iou; o2 = (float)glab[j];
        } else if (v && c > 1) {
            int p = atomicAdd(&s_nm, 1);
            s_mlist[p] = i;
        }
        out[i] = o0;
        out[NPRI + i] = o1;
        out[2 * NPRI + i] = o2;
    }
    __syncthreads();
    // ---- in-block multi resolution: one GT per thread, block argmin per prior ----
    const int nm = s_nm;
    const int j = tid;
    for (int m = 0; m < nm; ++m) {
        const int ii = s_mlist[m];
        float4 pb = pbp[2 * ii];
        float4 p2 = pbp[2 * ii + 1];
        float areap = (pb.z - pb.x) * (pb.w - pb.y);

        float4 g = gbox[j];
        float iw = fmaxf(fminf(pb.z, g.z) - fmaxf(pb.x, g.x), 0.0f);
        float ih = fmaxf(fminf(pb.w, g.w) - fmaxf(pb.y, g.y), 0.0f);
        float inter = iw * ih;
        float iou = inter / fmaxf(areap + gareas[j] - inter, 1e-6f);
        float dx = p2.x - gcxs[j], dy = p2.y - gcys[j];
        float dist = sqrtf(dx * dx + dy * dy) / p2.z;
        float soft = exp2f((dist - 3.0f) * L10);
        float l = scores[(size_t)ii * NCLS + glab[j]];
        float sig = 1.0f / (1.0f + expf(-l));
        float dd = iou - sig;
        float bce = fmaxf(l, 0.0f) - l * iou + log1pf(expf(-fabsf(l)));
        float cost = bce * (dd * dd) + (-logf(iou + EPS_F) * 3.0f) + soft;

        u64 key = (((u64)__float_as_uint(cost)) << 32) | (unsigned)j;
        u64 v = key;
        #pragma unroll
        for (int off = 32; off > 0; off >>= 1) {
            u64 o = __shfl_down(v, off, 64);
            v = (o < v) ? o : v;
        }
        if ((tid & 63) == 0) red4[tid >> 6] = v;
        __syncthreads();
        u64 best = red4[0];
        #pragma unroll
        for (int q = 1; q < 4; ++q) best = (red4[q] < best) ? red4[q] : best;
        if (key == best) {
            out[ii] = (float)(j + 1);
            out[NPRI + ii] = iou;
            out[2 * NPRI + ii] = (float)glab[j];
        }
        __syncthreads();
    }
}

extern "C" void kernel_launch(void* const* d_in, const int* in_sizes, int n_in,
                              void* d_out, int out_size, void* d_ws, size_t ws_size,
                              hipStream_t stream) {
    const float* scores = (const float*)d_in[0];
    const float* priors = (const float*)d_in[1];
    const float* pboxes = (const float*)d_in[2];
    const float* gt     = (const float*)d_in[3];
    const void*  labels = d_in[4];
    float* out = (float*)d_out;

    char* ws = (char*)d_ws;
    size_t off = 0;
    auto alloc = [&](size_t bytes) { size_t o = off; off = (off + bytes + 255) & ~(size_t)255; return o; };
    int*    flag      = (int*)(ws + alloc(4));
    int*    slice_done= (int*)(ws + alloc((size_t)NGT * 4));
    int*    count     = (int*)(ws + alloc((size_t)NPRI * 4));
    int*    firstgt   = (int*)(ws + alloc((size_t)NPRI * 4));
    float*  part_iou  = (float*)(ws + alloc((size_t)NGT * SLC * KTOP * 4));
    u64*    part_cost = (u64*)(ws + alloc((size_t)NGT * SLC * KTOP * 8));
    float4* pbp       = (float4*)(ws + alloc((size_t)NPRI * 32));
    (void)ws_size;

    hipLaunchKernelGGL(k_prep, dim3(PREP_BLKS), dim3(256), 0, stream,
                       priors, gt, labels, pboxes, pbp, count, firstgt, flag, slice_done);
    hipLaunchKernelGGL(k_scan, dim3(NGT, SLC), dim3(SCN_T), 0, stream,
                       scores, pbp, gt, labels, flag, part_iou, part_cost,
                       count, firstgt, slice_done);
    hipLaunchKernelGGL(k_assign, dim3((NPRI + 255) / 256), dim3(256), 0, stream,
                       scores, pbp, gt, labels, flag, count, firstgt, out);
}

// Round 8
// 144.451 us; speedup vs baseline: 1.0328x; 1.0009x over previous
//
#include <hip/hip_runtime.h>
#include <cstdint>

#define NPRI 33600
#define NGT  256
#define NCLS 80
#define KTOP 13
#define INF_F 1.0e8f
#define EPS_F 1e-7f
#define L10 3.3219280948873623f
#define SLC  4
#define SLEN (NPRI / SLC)          // 8400
#define SCN_T 512
#define NW8 (SCN_T / 64)           // 8 waves per block
#define NIT  ((SLEN + SCN_T - 1) / SCN_T)   // 17
#define CAPI 1536                  // per-slice positive-iou values
#define CAPC 512                   // per-slice cost candidates
#define RFIX 5.5f                  // fixed collect radius (strides)
#define PREP_BLKS ((NPRI + 255) / 256)
#define NEGINF __int_as_float(0xff800000)

typedef unsigned long long u64;

__device__ __forceinline__ int get_label(const void* p, int j, int is64) {
    if (is64) return (int)((const long long*)p)[j];
    return ((const int*)p)[j];
}

// ---------- agent-coherent (cross-XCD) scalar access: sc1 ops, NO L2 flush ----------
__device__ __forceinline__ void st_agent_f32(float* p, float v) {
    __hip_atomic_store(p, v, __ATOMIC_RELAXED, __HIP_MEMORY_SCOPE_AGENT);
}
__device__ __forceinline__ void st_agent_u64(u64* p, u64 v) {
    __hip_atomic_store(p, v, __ATOMIC_RELAXED, __HIP_MEMORY_SCOPE_AGENT);
}
__device__ __forceinline__ float ld_agent_f32(const float* p) {
    return __hip_atomic_load(p, __ATOMIC_RELAXED, __HIP_MEMORY_SCOPE_AGENT);
}
__device__ __forceinline__ u64 ld_agent_u64(const u64* p) {
    return __hip_atomic_load(p, __ATOMIC_RELAXED, __HIP_MEMORY_SCOPE_AGENT);
}

// ---------- wave helpers (reduce + broadcast) ----------
__device__ __forceinline__ float wave_max_bc_f32(float v) {
    #pragma unroll
    for (int off = 32; off > 0; off >>= 1) v = fmaxf(v, __shfl_down(v, off, 64));
    return __int_as_float(__builtin_amdgcn_readfirstlane(__float_as_int(v)));
}
__device__ __forceinline__ u64 wave_min_bc_u64(u64 v) {
    #pragma unroll
    for (int off = 32; off > 0; off >>= 1) { u64 o = __shfl_down(v, off, 64); v = (o < v) ? o : v; }
    unsigned lo = (unsigned)__builtin_amdgcn_readfirstlane((int)(v & 0xffffffffull));
    unsigned hi = (unsigned)__builtin_amdgcn_readfirstlane((int)(v >> 32));
    return (((u64)hi) << 32) | lo;
}
// f32 multiset per-wave top-13: ballot single-lane elimination preserves duplicates
template<int NSL, bool AGENT>
__device__ __forceinline__ void wave_merge_max13_f32(float (&l)[NSL], float* dst, int lane) {
    int p = 0;
    for (int r = 0; r < KTOP; ++r) {
        float cur = NEGINF;
        #pragma unroll
        for (int s = 0; s < NSL; ++s) if (s == p) cur = l[NSL - 1 - s];
        float bm = wave_max_bc_f32(cur);
        u64 m = __ballot(cur == bm && bm != NEGINF);
        int first = __ffsll(m) - 1;
        if (lane == first) p++;
        if (lane == 0) {
            if (AGENT) st_agent_f32(dst + r, bm);
            else dst[r] = bm;
        }
    }
}
// u64 per-wave top-13 min (keys idx-distinct -> single match per round)
template<int NSL>
__device__ __forceinline__ void wave_merge_minN(u64 (&l)[NSL], u64* dst, int lane) {
    int p = 0;
    for (int r = 0; r < KTOP; ++r) {
        u64 cur = ~0ull;
        #pragma unroll
        for (int s = 0; s < NSL; ++s) if (s == p) cur = l[s];
        u64 bm = wave_min_bc_u64(cur);
        if (cur == bm && bm != ~0ull) p++;
        if (lane == 0) dst[r] = bm;
    }
}

// ---------- exact formulas (verbatim: bit-identical selection) ----------
__device__ __forceinline__ float iou_exact(float4 pb, float areap, float gx1, float gy1,
                                           float gx2, float gy2, float areag) {
    float iw = fmaxf(fminf(pb.z, gx2) - fmaxf(pb.x, gx1), 0.0f);
    float ih = fmaxf(fminf(pb.w, gy2) - fmaxf(pb.y, gy1), 0.0f);
    float inter = iw * ih;
    return inter / fmaxf(areap + areag - inter, 1e-6f);
}
__device__ __forceinline__ float cost_exact(float4 p2, float gcx, float gcy,
                                            float l, float iou) {
    float dx = p2.x - gcx, dy = p2.y - gcy;
    float dist = sqrtf(dx * dx + dy * dy) / p2.z;
    float soft = exp2f((dist - 3.0f) * L10);
    float sig = 1.0f / (1.0f + expf(-l));
    float dd = iou - sig;
    float bce = fmaxf(l, 0.0f) - l * iou + log1pf(expf(-fabsf(l)));
    float iouc = -logf(iou + EPS_F) * 3.0f;
    return bce * (dd * dd) + iouc + soft;
}

// ---------- prep: detect int64 + init + valid mask + packed array ----------
// p2 = (px, py, stride, w) where w = valid ? (stride*RFIX)^2*(1+1e-5) : -1
__global__ __launch_bounds__(256) void k_prep(
        const float* __restrict__ priors, const float* __restrict__ gt,
        const void* labels, const float* __restrict__ pboxes,
        float4* __restrict__ pbp,
        int* count, int* firstgt, int* flag, int* slice_done) {
    __shared__ float4 gbox[NGT];
    __shared__ int    gpad[NGT];
    __shared__ int    bad;
    const int tid = threadIdx.x;
    const int b = blockIdx.x;
    if (b == 0 && tid == 0) bad = 0;
    if (b == 0) slice_done[tid] = 0;     // NGT == 256 == blockDim
    {
        float4 bx = ((const float4*)gt)[tid];
        gbox[tid] = bx;
        gpad[tid] = ((bx.x + bx.y + bx.z + bx.w) > 0.0f) ? 1 : 0;
    }
    __syncthreads();
    if (b == 0 && tid < 128) {
        long long v = ((const long long*)labels)[tid];   // first 1024B: in-bounds either layout
        if (v < 0 || v >= NCLS) atomicOr(&bad, 1);
    }
    int g = b * 256 + tid;
    if (g < NPRI) {
        count[g] = 0; firstgt[g] = NGT;
        float4 pr = ((const float4*)priors)[g];
        float px = pr.x, py = pr.y;
        int v = 0;
        for (int j = 0; j < NGT; ++j) {
            float4 bx = gbox[j];
            float m = fminf(fminf(px - bx.x, py - bx.y), fminf(bx.z - px, bx.w - py));
            if (m > 0.0f && gpad[j]) { v = 1; break; }
        }
        float rad = pr.z * RFIX;
        float w = v ? rad * rad * (1.0f + 1e-5f) : -1.0f;
        pbp[2 * g]     = ((const float4*)pboxes)[g];
        pbp[2 * g + 1] = make_float4(px, py, pr.z, w);
    }
    if (b == 0) {
        __syncthreads();
        if (tid == 0) *flag = bad ? 0 : 1;   // 1 => int64 layout
    }
}

// ---------- 4 slices x 512 thr per GT; grid = (SLC, NGT) so the 4 blocks
// co-resident on one CU are 4 GTs reading the SAME slice stream (L1 sharing,
// 4x less L2 demand) — with (NGT, SLC) they were 4 different slices. ----------
__global__ __launch_bounds__(SCN_T, 8) void k_scan(
        const float* __restrict__ scores,
        const float4* __restrict__ pbp,
        const float* __restrict__ gt, const void* labels, const int* flag,
        float* __restrict__ part_iou, u64* __restrict__ part_cost,
        int* count, int* firstgt, int* slice_done) {
    const int tid = threadIdx.x, lane = tid & 63, wid = tid >> 6;
    const int slice = blockIdx.x, j = blockIdx.y;   // SWAPPED vs round 7
    const int base = slice * SLEN;
    const int lim = base + SLEN;
    const int is64 = *flag;

    const float4 gb = ((const float4*)gt)[j];
    const float gx1 = gb.x, gy1 = gb.y, gx2 = gb.z, gy2 = gb.w;
    const float areag = (gx2 - gx1) * (gy2 - gy1);
    const float gcx = (gx1 + gx2) * 0.5f, gcy = (gy1 + gy2) * 0.5f;
    const int lab = get_label(labels, j, is64);

    __shared__ int s_ni, s_nc, s_mode, s_last;
    __shared__ float s_dmax;
    __shared__ float liou[CAPI];
    __shared__ int lcost[CAPC];
    __shared__ float wiof[NW8 * KTOP];   // fI fallback only
    __shared__ u64 wco[NW8 * KTOP];      // mode-2 fallback only
    __shared__ u64 csel[KTOP];
    if (tid == 0) { s_ni = 0; s_nc = 0; }
    __syncthreads();

    // ---- single pass, uniform 17-iter trip, 2-deep prefetch, plain atomics ----
    {
        const int i0 = base + tid;               // always < lim (SLEN > SCN_T)
        int ia1 = i0 + SCN_T;                    // < lim (tid+512 <= 1023 < 8400)
        float4 pb_c = pbp[2 * i0],  p2_c = pbp[2 * i0 + 1];
        float4 pb_n = pbp[2 * ia1], p2_n = pbp[2 * ia1 + 1];
        for (int it = 0; it < NIT; ++it) {
            int i = i0 + it * SCN_T;
            int ipre = i + 2 * SCN_T;
            int ic = (ipre < lim) ? ipre : i0;   // clamped prefetch address (always valid)
            float4 pb_p = pbp[2 * ic];
            float4 p2_p = pbp[2 * ic + 1];       // two loads in flight during compute

            if (i < lim) {
                float areap = (pb_c.z - pb_c.x) * (pb_c.w - pb_c.y);
                float iw = fmaxf(fminf(pb_c.z, gx2) - fmaxf(pb_c.x, gx1), 0.0f);
                float ih = fmaxf(fminf(pb_c.w, gy2) - fmaxf(pb_c.y, gy1), 0.0f);
                float inter = iw * ih;
                float iou = inter / fmaxf(areap + areag - inter, 1e-6f);   // exact
                if (iou > 0.0f) {
                    int p = atomicAdd(&s_ni, 1);
                    if (p < CAPI) liou[p] = iou;
                }
                float dx = p2_c.x - gcx, dy = p2_c.y - gcy;
                if (dx * dx + dy * dy <= p2_c.w) {
                    int p = atomicAdd(&s_nc, 1);
                    if (p < CAPC) lcost[p] = i;
                }
            }
            pb_c = pb_n; p2_c = p2_n;
            pb_n = pb_p; p2_n = p2_p;
        }
    }
    __syncthreads();
    const int ni = s_ni, nc = s_nc;
    const int ncc = (nc < CAPC) ? nc : CAPC;
    const bool fI = (ni > CAPI);

    // ---- parallel single-wave merges: wave 0 = cost, wave 1 = iou ----
    if (wid == 0) {
        u64 lf[KTOP];
        #pragma unroll
        for (int s = 0; s < KTOP; ++s) lf[s] = ~0ull;
        for (int k = lane; k < ncc; k += 64) {   // <=8 per lane; 13-deep list complete
            int i = lcost[k];
            float4 pb = pbp[2 * i];
            float4 p2 = pbp[2 * i + 1];
            float areap = (pb.z - pb.x) * (pb.w - pb.y);
            float iou = iou_exact(pb, areap, gx1, gy1, gx2, gy2, areag);
            float ec = cost_exact(p2, gcx, gcy, scores[(size_t)i * NCLS + lab], iou);
            u64 ck = (((u64)__float_as_uint(ec)) << 32) | (unsigned)i;
            if (ck < lf[KTOP - 1]) {
                lf[KTOP - 1] = ck;
                #pragma unroll
                for (int s = KTOP - 1; s > 0; --s)
                    if (lf[s] < lf[s - 1]) { u64 t = lf[s]; lf[s] = lf[s - 1]; lf[s - 1] = t; }
            }
        }
        wave_merge_minN<KTOP>(lf, csel, lane);
        if (lane == 0) {
            u64 tk = csel[KTOP - 1];
            int mode; float dmax = 0.0f;
            if (tk == ~0ull) mode = 2;               // <13 candidates in RFIX ball
            else {
                float tau = __uint_as_float((unsigned)(tk >> 32));
                if (!(tau < 9.0e7f)) mode = 2;       // INF-ambiguity zone
                else {
                    dmax = 3.0f + __log2f(tau + 1e-5f) * (1.0f / L10) + 4e-3f;
                    mode = (dmax > RFIX || nc > CAPC) ? 1 : 0;
                }
            }
            s_mode = mode; s_dmax = dmax;
        }
    } else if (wid == 1 && !fI) {
        float lf[KTOP];
        #pragma unroll
        for (int s = 0; s < KTOP; ++s) lf[s] = NEGINF;
        int nn = (ni < CAPI) ? ni : CAPI;
        for (int k = lane; k < nn; k += 64) {    // <=24 per lane; 13-deep retains any lane's top-13
            float v = liou[k];
            if (v > lf[0]) {
                lf[0] = v;
                #pragma unroll
                for (int s = 0; s < KTOP - 1; ++s)
                    if (lf[s] > lf[s + 1]) { float t = lf[s]; lf[s] = lf[s + 1]; lf[s + 1] = t; }
            }
        }
        wave_merge_max13_f32<KTOP, true>(lf, part_iou + ((size_t)j * SLC + slice) * KTOP, lane);
    }
    __syncthreads();

    if (fI) {   // rare: iou list overflowed -> exact full-slice scan (two-stage merge)
        float lf[KTOP];
        #pragma unroll
        for (int s = 0; s < KTOP; ++s) lf[s] = NEGINF;
        for (int i = base + tid; i < lim; i += SCN_T) {
            float4 pb = pbp[2 * i];
            float areap = (pb.z - pb.x) * (pb.w - pb.y);
            float iou = iou_exact(pb, areap, gx1, gy1, gx2, gy2, areag);
            if (iou > 0.0f && iou > lf[0]) {
                lf[0] = iou;
                #pragma unroll
                for (int s = 0; s < KTOP - 1; ++s)
                    if (lf[s] > lf[s + 1]) { float t = lf[s]; lf[s] = lf[s + 1]; lf[s + 1] = t; }
            }
        }
        wave_merge_max13_f32<KTOP, false>(lf, &wiof[wid * KTOP], lane);
        __syncthreads();
        if (wid == 0) {
            float* dpi = part_iou + ((size_t)j * SLC + slice) * KTOP;
            int p = 0;
            for (int r = 0; r < KTOP; ++r) {
                float cur = (lane < NW8 && p < KTOP) ? wiof[lane * KTOP + p] : NEGINF;
                float bm = wave_max_bc_f32(cur);
                u64 m = __ballot(cur == bm && bm != NEGINF);
                int first = __ffsll(m) - 1;
                if (lane == first) p++;
                if (lane == 0) st_agent_f32(dpi + r, bm);
            }
        }
        __syncthreads();
    }

    int mode = s_mode;
    if (mode == 1) {   // re-collect at the sound radius Dmax' (rare)
        const float dmax = s_dmax;
        if (tid == 0) s_nc = 0;
        __syncthreads();
        for (int i = base + tid; i < lim; i += SCN_T) {
            float4 p2 = pbp[2 * i + 1];
            if (p2.w > 0.0f) {
                float dx = p2.x - gcx, dy = p2.y - gcy;
                float rad = p2.z * dmax;
                if (dx * dx + dy * dy <= rad * rad * (1.0f + 1e-5f)) {
                    int p = atomicAdd(&s_nc, 1);
                    if (p < CAPC) lcost[p] = i;
                }
            }
        }
        __syncthreads();
        int nc2 = s_nc;
        if (nc2 <= CAPC) {
            if (wid == 0) {
                u64 lf[KTOP];
                #pragma unroll
                for (int s = 0; s < KTOP; ++s) lf[s] = ~0ull;
                for (int k = lane; k < nc2; k += 64) {
                    int i = lcost[k];
                    float4 pb = pbp[2 * i];
                    float4 p2 = pbp[2 * i + 1];
                    float areap = (pb.z - pb.x) * (pb.w - pb.y);
                    float iou = iou_exact(pb, areap, gx1, gy1, gx2, gy2, areag);
                    float ec = cost_exact(p2, gcx, gcy, scores[(size_t)i * NCLS + lab], iou);
                    u64 ck = (((u64)__float_as_uint(ec)) << 32) | (unsigned)i;
                    if (ck < lf[KTOP - 1]) {
                        lf[KTOP - 1] = ck;
                        #pragma unroll
                        for (int s = KTOP - 1; s > 0; --s)
                            if (lf[s] < lf[s - 1]) { u64 t = lf[s]; lf[s] = lf[s - 1]; lf[s - 1] = t; }
                    }
                }
                wave_merge_minN<KTOP>(lf, csel, lane);
            }
        } else {
            mode = 2;   // uniform (s_nc shared)
        }
        __syncthreads();
    }
    if (mode == 2) {   // exact full slice scan (correctness net)
        u64 lf[KTOP];
        #pragma unroll
        for (int s = 0; s < KTOP; ++s) lf[s] = ~0ull;
        for (int i = base + tid; i < lim; i += SCN_T) {
            float4 pb = pbp[2 * i];
            float4 p2 = pbp[2 * i + 1];
            float areap = (pb.z - pb.x) * (pb.w - pb.y);
            float iou = iou_exact(pb, areap, gx1, gy1, gx2, gy2, areag);
            float ec = INF_F;
            if (p2.w > 0.0f) ec = cost_exact(p2, gcx, gcy, scores[(size_t)i * NCLS + lab], iou);
            u64 k2 = (((u64)__float_as_uint(ec)) << 32) | (unsigned)i;
            if (k2 < lf[KTOP - 1]) {
                lf[KTOP - 1] = k2;
                #pragma unroll
                for (int s = KTOP - 1; s > 0; --s)
                    if (lf[s] < lf[s - 1]) { u64 t = lf[s]; lf[s] = lf[s - 1]; lf[s - 1] = t; }
            }
        }
        wave_merge_minN<KTOP>(lf, &wco[wid * KTOP], lane);
        __syncthreads();
        if (wid == 0) {
            int p = 0;
            for (int r = 0; r < KTOP; ++r) {
                u64 cur = (lane < NW8 && p < KTOP) ? wco[lane * KTOP + p] : ~0ull;
                u64 bm = wave_min_bc_u64(cur);
                if (cur == bm && bm != ~0ull) p++;
                if (lane == 0) csel[r] = bm;
            }
        }
        __syncthreads();
    }
    if (tid < KTOP) {
        u64* dpc = part_cost + ((size_t)j * SLC + slice) * KTOP;
        st_agent_u64(dpc + tid, csel[tid]);
    }

    // ---- fused per-GT merge: last-finishing slice merges all SLC slices.
    // All part stores above are sc1 (agent-coherent); __syncthreads drains
    // vmcnt(0) before its barrier -> visible before the flag bump. NO
    // __threadfence (full-L2 wbl2/inv) anywhere — that was the round-1 regression.
    asm volatile("s_waitcnt vmcnt(0)" ::: "memory");
    __syncthreads();
    if (tid == 0) s_last = (atomicAdd(&slice_done[j], 1) == SLC - 1) ? 1 : 0;
    __syncthreads();
    if (s_last && wid == 0) {
        const int l = lane;
        float vi = (l < SLC * KTOP) ? ld_agent_f32(part_iou + (size_t)j * SLC * KTOP + l) : NEGINF;
        float tsum = 0.0f;
        for (int r = 0; r < KTOP; ++r) {
            float bm = wave_max_bc_f32(vi);
            u64 mmask = __ballot(vi == bm && bm != NEGINF);
            int first = __ffsll(mmask) - 1;
            if (l == first) vi = NEGINF;
            tsum += (bm == NEGINF) ? 0.0f : bm;   // descending-order sum (missing = 0, as ref)
        }
        int ks = (int)tsum;
        if (ks < 1) ks = 1;
        u64 kc = (l < SLC * KTOP) ? ld_agent_u64(part_cost + (size_t)j * SLC * KTOP + l) : ~0ull;
        u64 mine = ~0ull;
        for (int r = 0; r < KTOP; ++r) {
            u64 bm = wave_min_bc_u64(kc);
            if (kc == bm && bm != ~0ull) kc = ~0ull;
            if (l == r) mine = bm;
        }
        if (l < KTOP && l < ks && mine != ~0ull) {
            int idx = (int)(unsigned)(mine & 0xFFFFFFFFull);
            atomicAdd(&count[idx], 1);
            atomicMin(&firstgt[idx], j);
        }
    }
}

// ---------- per-prior finalize; multi-matched priors resolved in-block ----------
__global__ __launch_bounds__(256) void k_assign(
        const float* __restrict__ scores,
        const float4* __restrict__ pbp, const float* __restrict__ gt,
        const void* labels, const int* flag,
        const int* __restrict__ count, const int* __restrict__ firstgt,
        float* __restrict__ out) {
    __shared__ float4 gbox[NGT];
    __shared__ int glab[NGT];
    __shared__ float gcxs[NGT], gcys[NGT], gareas[NGT];
    __shared__ int s_nm;
    __shared__ int s_mlist[256];
    __shared__ u64 red4[4];
    const int tid = threadIdx.x;
    const int is64 = *flag;
    {
        float4 b = ((const float4*)gt)[tid];
        gbox[tid] = b;
        glab[tid] = get_label(labels, tid, is64);
        gcxs[tid] = (b.x + b.z) * 0.5f;
        gcys[tid] = (b.y + b.w) * 0.5f;
        gareas[tid] = (b.z - b.x) * (b.w - b.y);
    }
    if (tid == 0) s_nm = 0;
    __syncthreads();
    const int i = blockIdx.x * 256 + tid;
    const bool act = (i < NPRI);
    if (act) {
        float4 p2 = pbp[2 * i + 1];
        int v = (p2.w > 0.0f) ? 1 : 0;
        int c = count[i];
        float o0 = 0.0f, o1 = -INF_F, o2 = -1.0f;
        if (v && c == 1) {
            int j = firstgt[i];
            float4 pb = pbp[2 * i];
            float areap = (pb.z - pb.x) * (pb.w - pb.y);
            float4 g = gbox[j];
            float iw = fmaxf(fminf(pb.z, g.z) - fmaxf(pb.x, g.x), 0.0f);
            float ih = fmaxf(fminf(pb.w, g.w) - fmaxf(pb.y, g.y), 0.0f);
            float inter = iw * ih;
            float iou = inter / fmaxf(areap + gareas[j] - inter, 1e-6f);
            o0 = (float)(j + 1); o1 = iou; o2 = (float)glab[j];
        } else if (v && c > 1) {
            int p = atomicAdd(&s_nm, 1);
            s_mlist[p] = i;
        }
        out[i] = o0;
        out[NPRI + i] = o1;
        out[2 * NPRI + i] = o2;
    }
    __syncthreads();
    // ---- in-block multi resolution: one GT per thread, block argmin per prior ----
    const int nm = s_nm;
    const int j = tid;
    for (int m = 0; m < nm; ++m) {
        const int ii = s_mlist[m];
        float4 pb = pbp[2 * ii];
        float4 p2 = pbp[2 * ii + 1];
        float areap = (pb.z - pb.x) * (pb.w - pb.y);

        float4 g = gbox[j];
        float iw = fmaxf(fminf(pb.z, g.z) - fmaxf(pb.x, g.x), 0.0f);
        float ih = fmaxf(fminf(pb.w, g.w) - fmaxf(pb.y, g.y), 0.0f);
        float inter = iw * ih;
        float iou = inter / fmaxf(areap + gareas[j] - inter, 1e-6f);
        float dx = p2.x - gcxs[j], dy = p2.y - gcys[j];
        float dist = sqrtf(dx * dx + dy * dy) / p2.z;
        float soft = exp2f((dist - 3.0f) * L10);
        float l = scores[(size_t)ii * NCLS + glab[j]];
        float sig = 1.0f / (1.0f + expf(-l));
        float dd = iou - sig;
        float bce = fmaxf(l, 0.0f) - l * iou + log1pf(expf(-fabsf(l)));
        float cost = bce * (dd * dd) + (-logf(iou + EPS_F) * 3.0f) + soft;

        u64 key = (((u64)__float_as_uint(cost)) << 32) | (unsigned)j;
        u64 v = key;
        #pragma unroll
        for (int off = 32; off > 0; off >>= 1) {
            u64 o = __shfl_down(v, off, 64);
            v = (o < v) ? o : v;
        }
        if ((tid & 63) == 0) red4[tid >> 6] = v;
        __syncthreads();
        u64 best = red4[0];
        #pragma unroll
        for (int q = 1; q < 4; ++q) best = (red4[q] < best) ? red4[q] : best;
        if (key == best) {
            out[ii] = (float)(j + 1);
            out[NPRI + ii] = iou;
            out[2 * NPRI + ii] = (float)glab[j];
        }
        __syncthreads();
    }
}

extern "C" void kernel_launch(void* const* d_in, const int* in_sizes, int n_in,
                              void* d_out, int out_size, void* d_ws, size_t ws_size,
                              hipStream_t stream) {
    const float* scores = (const float*)d_in[0];
    const float* priors = (const float*)d_in[1];
    const float* pboxes = (const float*)d_in[2];
    const float* gt     = (const float*)d_in[3];
    const void*  labels = d_in[4];
    float* out = (float*)d_out;

    char* ws = (char*)d_ws;
    size_t off = 0;
    auto alloc = [&](size_t bytes) { size_t o = off; off = (off + bytes + 255) & ~(size_t)255; return o; };
    int*    flag      = (int*)(ws + alloc(4));
    int*    slice_done= (int*)(ws + alloc((size_t)NGT * 4));
    int*    count     = (int*)(ws + alloc((size_t)NPRI * 4));
    int*    firstgt   = (int*)(ws + alloc((size_t)NPRI * 4));
    float*  part_iou  = (float*)(ws + alloc((size_t)NGT * SLC * KTOP * 4));
    u64*    part_cost = (u64*)(ws + alloc((size_t)NGT * SLC * KTOP * 8));
    float4* pbp       = (float4*)(ws + alloc((size_t)NPRI * 32));
    (void)ws_size;

    hipLaunchKernelGGL(k_prep, dim3(PREP_BLKS), dim3(256), 0, stream,
                       priors, gt, labels, pboxes, pbp, count, firstgt, flag, slice_done);
    hipLaunchKernelGGL(k_scan, dim3(SLC, NGT), dim3(SCN_T), 0, stream,
                       scores, pbp, gt, labels, flag, part_iou, part_cost,
                       count, firstgt, slice_done);
    hipLaunchKernelGGL(k_assign, dim3((NPRI + 255) / 256), dim3(256), 0, stream,
                       scores, pbp, gt, labels, flag, count, firstgt, out);
}